// Round 1
// baseline (375.286 us; speedup 1.0000x reference)
//
#include <hip/hip_runtime.h>
#include <hip/hip_bf16.h>
#include <stdint.h>

// Problem: y[b,s,o] = sum_k x[b,s,k] * W[o,k] + bias[o]
// W dequantized from packed FP4 (E2M1, two nibbles per byte stored as int32)
// with per-32-element fp32 scales.
// M = 4*2048 = 8192, N = OUT = 4096, K = IN = 4096.

#define M_DIM 8192
#define N_DIM 4096
#define K_DIM 4096
#define NBLK_W (N_DIM * K_DIM / 32)   // 524288 scale blocks

#define BM 128
#define BN 128
#define BK 32

typedef __bf16 bf16x8 __attribute__((ext_vector_type(8)));
typedef float  f32x4  __attribute__((ext_vector_type(4)));

// ---------- helpers ----------

__device__ __forceinline__ uint16_t f32_to_bf16_rn(float f) {
  uint32_t u = __float_as_uint(f);
  uint32_t r = (u + 0x7FFFu + ((u >> 16) & 1u)) >> 16;
  return (uint16_t)r;
}

// e0 goes to low 16 bits (lower address), e1 to high 16 bits
__device__ __forceinline__ uint32_t pack_bf16x2(float e0, float e1) {
  return (uint32_t)f32_to_bf16_rn(e0) | ((uint32_t)f32_to_bf16_rn(e1) << 16);
}

// FP4 E2M1 decode: value = sign * mag, mag in {0,0.5,1,1.5,2,3,4,6}
__device__ __forceinline__ float fp4_to_f32(int nib) {
  uint32_t e = (uint32_t)(nib >> 1) & 3u;
  uint32_t m = (uint32_t)nib & 1u;
  uint32_t s = (uint32_t)(nib >> 3) & 1u;
  uint32_t bits = e ? (((126u + e) << 23) | (m << 22)) : (m ? 0x3F000000u : 0u);
  bits |= s << 31;
  return __uint_as_float(bits);
}

__device__ __forceinline__ void gload_lds16(const void* g, void* lds) {
  __builtin_amdgcn_global_load_lds(
      (const __attribute__((address_space(1))) unsigned int*)g,
      (__attribute__((address_space(3))) unsigned int*)lds,
      16, 0, 0);
}

// ---------- kernel 1: dequant W -> bf16 [N_DIM][K_DIM] ----------
// one thread per 32-weight scale block: reads 16 int32 (one byte each),
// writes 32 bf16 (64B).
__global__ __launch_bounds__(256) void dequant_w(const int* __restrict__ q,
                                                 const float* __restrict__ scales,
                                                 uint32_t* __restrict__ W /* as u32 pairs */) {
  int b = blockIdx.x * 256 + threadIdx.x;   // 0 .. NBLK_W-1
  float sc = scales[b];
  const int4* q4 = reinterpret_cast<const int4*>(q) + (size_t)b * 4;
  int4* dst = reinterpret_cast<int4*>(W + (size_t)b * 16);
#pragma unroll
  for (int i = 0; i < 4; ++i) {
    int4 v = q4[i];
    int b0 = v.x & 0xFF, b1 = v.y & 0xFF, b2 = v.z & 0xFF, b3 = v.w & 0xFF;
    // high nibble is element 2i, low nibble is 2i+1
    uint32_t p0 = pack_bf16x2(fp4_to_f32((b0 >> 4) & 15) * sc, fp4_to_f32(b0 & 15) * sc);
    uint32_t p1 = pack_bf16x2(fp4_to_f32((b1 >> 4) & 15) * sc, fp4_to_f32(b1 & 15) * sc);
    uint32_t p2 = pack_bf16x2(fp4_to_f32((b2 >> 4) & 15) * sc, fp4_to_f32(b2 & 15) * sc);
    uint32_t p3 = pack_bf16x2(fp4_to_f32((b3 >> 4) & 15) * sc, fp4_to_f32(b3 & 15) * sc);
    int4 o;
    o.x = (int)p0; o.y = (int)p1; o.z = (int)p2; o.w = (int)p3;
    dst[i] = o;
  }
}

// ---------- kernel 2: cvt x fp32 -> bf16 ----------
__global__ __launch_bounds__(256) void cvt_x(const float* __restrict__ x,
                                             uint32_t* __restrict__ xb) {
  size_t i = ((size_t)blockIdx.x * 256 + threadIdx.x) * 8;
  float4 a = *reinterpret_cast<const float4*>(x + i);
  float4 c = *reinterpret_cast<const float4*>(x + i + 4);
  int4 o;
  o.x = (int)pack_bf16x2(a.x, a.y);
  o.y = (int)pack_bf16x2(a.z, a.w);
  o.z = (int)pack_bf16x2(c.x, c.y);
  o.w = (int)pack_bf16x2(c.z, c.w);
  *reinterpret_cast<int4*>(xb + i / 2) = o;
}

// ---------- kernel 3: bf16 B^T GEMM (m97 structure) ----------
// C[m][n] = sum_k A[m][k] * B[n][k] + bias[n]
// 256 threads = 4 waves in 2x2; each wave does 64x64 via 4x4 frags of
// mfma_f32_16x16x32_bf16. BK=32 per step, global_load_lds width 16.
__global__ __launch_bounds__(256) void gemm_bt_bf16(const __bf16* __restrict__ A,
                                                    const __bf16* __restrict__ B,
                                                    const float* __restrict__ bias,
                                                    float* __restrict__ C) {
  __shared__ __align__(16) __bf16 As[BM][BK];
  __shared__ __align__(16) __bf16 Bs[BN][BK];

  const int tid  = threadIdx.x;
  const int wave = tid >> 6;
  const int lane = tid & 63;
  const int bn = blockIdx.x;
  const int bm = blockIdx.y;

  const int K = K_DIM, N = N_DIM;

  // staging addresses: thread t covers row = issue*64 + t/4, col8 = (t%4)*8
  const __bf16* gA0 = A + ((size_t)(bm * BM + (tid >> 2))) * K + (tid & 3) * 8;
  const __bf16* gA1 = gA0 + (size_t)64 * K;
  const __bf16* gB0 = B + ((size_t)(bn * BN + (tid >> 2))) * K + (tid & 3) * 8;
  const __bf16* gB1 = gB0 + (size_t)64 * K;

  // LDS dest: wave-uniform base; lane writes base + lane*16 (linear layout)
  char* ldsA0 = (char*)(&As[0][0]) + wave * 1024;
  char* ldsA1 = ldsA0 + 4096;
  char* ldsB0 = (char*)(&Bs[0][0]) + wave * 1024;
  char* ldsB1 = ldsB0 + 4096;

  f32x4 acc[4][4];
#pragma unroll
  for (int i = 0; i < 4; ++i)
#pragma unroll
    for (int j = 0; j < 4; ++j)
      acc[i][j] = (f32x4){0.f, 0.f, 0.f, 0.f};

  const int l16 = lane & 15;
  const int kg  = lane >> 4;           // 0..3 -> k chunk of 8
  const int wM  = (wave >> 1) * 64;
  const int wN  = (wave & 1) * 64;

  for (int kt = 0; kt < K; kt += BK) {
    gload_lds16(gA0 + kt, ldsA0);
    gload_lds16(gA1 + kt, ldsA1);
    gload_lds16(gB0 + kt, ldsB0);
    gload_lds16(gB1 + kt, ldsB1);
    __syncthreads();   // drains vmcnt -> staged data visible

    bf16x8 af[4], bf[4];
#pragma unroll
    for (int f = 0; f < 4; ++f) {
      af[f] = *reinterpret_cast<const bf16x8*>(&As[wM + f * 16 + l16][kg * 8]);
      bf[f] = *reinterpret_cast<const bf16x8*>(&Bs[wN + f * 16 + l16][kg * 8]);
    }
#pragma unroll
    for (int fm = 0; fm < 4; ++fm)
#pragma unroll
      for (int fn = 0; fn < 4; ++fn)
        acc[fm][fn] = __builtin_amdgcn_mfma_f32_16x16x32_bf16(af[fm], bf[fn], acc[fm][fn], 0, 0, 0);

    __syncthreads();   // all reads done before next stage overwrites
  }

  // epilogue: C/D layout col = lane&15, row = (lane>>4)*4 + reg
#pragma unroll
  for (int fm = 0; fm < 4; ++fm) {
    const int mbase = bm * BM + wM + fm * 16 + kg * 4;
#pragma unroll
    for (int fn = 0; fn < 4; ++fn) {
      const int n = bn * BN + wN + fn * 16 + l16;
      const float bv = bias[n];
#pragma unroll
      for (int r = 0; r < 4; ++r)
        C[(size_t)(mbase + r) * N + n] = acc[fm][fn][r] + bv;
    }
  }
}

// ---------- fallback (ws too small): fused naive, correct but slow ----------
__global__ __launch_bounds__(256) void naive_fused(const float* __restrict__ x,
                                                   const int* __restrict__ q,
                                                   const float* __restrict__ scales,
                                                   const float* __restrict__ bias,
                                                   float* __restrict__ out) {
  __shared__ float xs[K_DIM];
  const int m = blockIdx.y;
  const int n = blockIdx.x * 256 + threadIdx.x;
  for (int k = threadIdx.x; k < K_DIM; k += 256)
    xs[k] = x[(size_t)m * K_DIM + k];
  __syncthreads();

  const int4* q4 = reinterpret_cast<const int4*>(q) + (size_t)n * 512;
  float acc = 0.f;
  float sc = 0.f;
  for (int c = 0; c < 512; ++c) {
    if ((c & 3) == 0) sc = scales[n * 128 + (c >> 2)];
    int4 v = q4[c];
    int bytes0 = v.x & 0xFF, bytes1 = v.y & 0xFF, bytes2 = v.z & 0xFF, bytes3 = v.w & 0xFF;
    int k = c * 8;
    acc += xs[k + 0] * fp4_to_f32((bytes0 >> 4) & 15) * sc;
    acc += xs[k + 1] * fp4_to_f32(bytes0 & 15) * sc;
    acc += xs[k + 2] * fp4_to_f32((bytes1 >> 4) & 15) * sc;
    acc += xs[k + 3] * fp4_to_f32(bytes1 & 15) * sc;
    acc += xs[k + 4] * fp4_to_f32((bytes2 >> 4) & 15) * sc;
    acc += xs[k + 5] * fp4_to_f32(bytes2 & 15) * sc;
    acc += xs[k + 6] * fp4_to_f32((bytes3 >> 4) & 15) * sc;
    acc += xs[k + 7] * fp4_to_f32(bytes3 & 15) * sc;
  }
  out[(size_t)m * N_DIM + n] = acc + bias[n];
}

// ---------- launch ----------
extern "C" void kernel_launch(void* const* d_in, const int* in_sizes, int n_in,
                              void* d_out, int out_size, void* d_ws, size_t ws_size,
                              hipStream_t stream) {
  const float* x    = (const float*)d_in[0];
  const int*   q    = (const int*)d_in[1];
  const float* sc   = (const float*)d_in[2];
  const float* bias = (const float*)d_in[3];
  float* out = (float*)d_out;

  const size_t xb_bytes = (size_t)M_DIM * K_DIM * 2;   // 64 MB
  const size_t w_bytes  = (size_t)N_DIM * K_DIM * 2;   // 32 MB

  if (ws_size >= xb_bytes + w_bytes) {
    uint32_t* xb = (uint32_t*)d_ws;                       // bf16 x, as u32 pairs
    uint32_t* W  = (uint32_t*)((char*)d_ws + xb_bytes);   // bf16 W

    dequant_w<<<NBLK_W / 256, 256, 0, stream>>>(q, sc, W);
    cvt_x<<<(M_DIM * (size_t)K_DIM / 8) / 256, 256, 0, stream>>>(x, xb);

    dim3 grid(N_DIM / BN, M_DIM / BM);
    gemm_bt_bf16<<<grid, 256, 0, stream>>>((const __bf16*)xb, (const __bf16*)W, bias, out);
  } else {
    dim3 grid(N_DIM / 256, M_DIM);
    naive_fused<<<grid, 256, 0, stream>>>(x, q, sc, bias, out);
  }
}

// Round 2
// 302.009 us; speedup vs baseline: 1.2426x; 1.2426x over previous
//
#include <hip/hip_runtime.h>
#include <hip/hip_bf16.h>
#include <stdint.h>

// y[b,s,o] = sum_k x[b,s,k] * W[o,k] + bias[o]
// W from packed FP4 (E2M1 nibbles in int32 bytes) * per-32 fp32 scales.
// M = 8192, N = 4096, K = 4096.

#define M_DIM 8192
#define N_DIM 4096
#define K_DIM 4096
#define NBLK_W (N_DIM * K_DIM / 32)

typedef __bf16 bf16x8 __attribute__((ext_vector_type(8)));
typedef float  f32x4  __attribute__((ext_vector_type(4)));

// ---------------- helpers ----------------

__device__ __forceinline__ uint16_t f32_to_bf16_rn(float f) {
  uint32_t u = __float_as_uint(f);
  uint32_t r = (u + 0x7FFFu + ((u >> 16) & 1u)) >> 16;
  return (uint16_t)r;
}
__device__ __forceinline__ uint32_t pack_bf16x2(float e0, float e1) {
  return (uint32_t)f32_to_bf16_rn(e0) | ((uint32_t)f32_to_bf16_rn(e1) << 16);
}
__device__ __forceinline__ float fp4_to_f32(int nib) {
  uint32_t e = (uint32_t)(nib >> 1) & 3u;
  uint32_t m = (uint32_t)nib & 1u;
  uint32_t s = (uint32_t)(nib >> 3) & 1u;
  uint32_t bits = e ? (((126u + e) << 23) | (m << 22)) : (m ? 0x3F000000u : 0u);
  bits |= s << 31;
  return __uint_as_float(bits);
}
__device__ __forceinline__ void gload_lds16(const void* g, void* lds) {
  __builtin_amdgcn_global_load_lds(
      (const __attribute__((address_space(1))) unsigned int*)g,
      (__attribute__((address_space(3))) unsigned int*)lds,
      16, 0, 0);
}

// ---------------- kernel 1: dequant W -> bf16 [N][K] ----------------
__global__ __launch_bounds__(256) void dequant_w(const int* __restrict__ q,
                                                 const float* __restrict__ scales,
                                                 uint32_t* __restrict__ W) {
  int b = blockIdx.x * 256 + threadIdx.x;
  float sc = scales[b];
  const int4* q4 = reinterpret_cast<const int4*>(q) + (size_t)b * 4;
  int4* dst = reinterpret_cast<int4*>(W + (size_t)b * 16);
#pragma unroll
  for (int i = 0; i < 4; ++i) {
    int4 v = q4[i];
    int b0 = v.x & 0xFF, b1 = v.y & 0xFF, b2 = v.z & 0xFF, b3 = v.w & 0xFF;
    uint32_t p0 = pack_bf16x2(fp4_to_f32((b0 >> 4) & 15) * sc, fp4_to_f32(b0 & 15) * sc);
    uint32_t p1 = pack_bf16x2(fp4_to_f32((b1 >> 4) & 15) * sc, fp4_to_f32(b1 & 15) * sc);
    uint32_t p2 = pack_bf16x2(fp4_to_f32((b2 >> 4) & 15) * sc, fp4_to_f32(b2 & 15) * sc);
    uint32_t p3 = pack_bf16x2(fp4_to_f32((b3 >> 4) & 15) * sc, fp4_to_f32(b3 & 15) * sc);
    int4 o; o.x = (int)p0; o.y = (int)p1; o.z = (int)p2; o.w = (int)p3;
    dst[i] = o;
  }
}

// ---------------- kernel 2: cvt x fp32 -> bf16 ----------------
__global__ __launch_bounds__(256) void cvt_x(const float* __restrict__ x,
                                             uint32_t* __restrict__ xb) {
  size_t i = ((size_t)blockIdx.x * 256 + threadIdx.x) * 8;
  float4 a = *reinterpret_cast<const float4*>(x + i);
  float4 c = *reinterpret_cast<const float4*>(x + i + 4);
  int4 o;
  o.x = (int)pack_bf16x2(a.x, a.y);
  o.y = (int)pack_bf16x2(a.z, a.w);
  o.z = (int)pack_bf16x2(c.x, c.y);
  o.w = (int)pack_bf16x2(c.z, c.w);
  *reinterpret_cast<int4*>(xb + i / 2) = o;
}

// ---------------- kernel 3: 256x256 8-phase bf16 GEMM (B^T) ----------------
// C[m][n] = sum_k A[m][k]*B[n][k] + bias[n]
// 512 threads = 8 waves (2 M x 4 N). Per-wave: 128x64 out, acc[8][4] f32x4.
// LDS 128 KiB: 2 buffers x { A0,A1,B0,B1 halves of 128x64 bf16 (16 KiB) }.
// st_16x32 swizzle: phys_byte = logical_byte ^ (((logical_byte>>9)&1)<<5),
// applied via pre-swizzled global source (linear global_load_lds dest) and
// swizzled ds_read addresses.

#define BUF0 0
#define BUF1 65536
#define A0OFF 0
#define A1OFF 16384
#define B0OFF 32768
#define B1OFF 49152
#define AH1 (128 * 4096)       // +128 rows (elements)
#define NITER 32               // 64 K-tiles, 2 per iter

#define BARRIER()   asm volatile("s_barrier" ::: "memory")
#define WAIT_LGKM0() do { asm volatile("s_waitcnt lgkmcnt(0)" ::: "memory"); \
                          __builtin_amdgcn_sched_barrier(0); } while (0)
#define WAIT_VM4()  asm volatile("s_waitcnt vmcnt(4)" ::: "memory")
#define WAIT_VM0()  asm volatile("s_waitcnt vmcnt(0)" ::: "memory")

template <int P>
__device__ __forceinline__ void phase_lda(bf16x8 (&aA)[2][2], const char* sm,
                                          int cb, uint32_t a_rd) {
  aA[0][0] = *(const bf16x8*)(sm + cb + a_rd + (2 * P) * 2048);
  aA[0][1] = *(const bf16x8*)(sm + cb + a_rd + (2 * P) * 2048 + 64);
  aA[1][0] = *(const bf16x8*)(sm + cb + a_rd + (2 * P + 1) * 2048);
  aA[1][1] = *(const bf16x8*)(sm + cb + a_rd + (2 * P + 1) * 2048 + 64);
}

__device__ __forceinline__ void phase_ldb(bf16x8 (&bfr)[4][2], const char* sm,
                                          int cb, uint32_t b_rd) {
#pragma unroll
  for (int nf = 0; nf < 4; ++nf) {
    bfr[nf][0] = *(const bf16x8*)(sm + cb + b_rd + nf * 2048);
    bfr[nf][1] = *(const bf16x8*)(sm + cb + b_rd + nf * 2048 + 64);
  }
}

template <int P>
__device__ __forceinline__ void phase_mfma(f32x4 (&acc)[8][4],
                                           const bf16x8 (&aA)[2][2],
                                           const bf16x8 (&bfr)[4][2]) {
#pragma unroll
  for (int nf = 0; nf < 4; ++nf)
#pragma unroll
    for (int kk = 0; kk < 2; ++kk) {
      acc[2 * P][nf] = __builtin_amdgcn_mfma_f32_16x16x32_bf16(
          aA[0][kk], bfr[nf][kk], acc[2 * P][nf], 0, 0, 0);
      acc[2 * P + 1][nf] = __builtin_amdgcn_mfma_f32_16x16x32_bf16(
          aA[1][kk], bfr[nf][kk], acc[2 * P + 1][nf], 0, 0, 0);
    }
}

// stage one 128x64 half-tile: 2 x global_load_lds (s=0: rows 0-63, s=1: 64-127)
__device__ __forceinline__ void stage_half_tile(const __bf16* gsrc, char* lds_dst) {
  gload_lds16(gsrc, lds_dst);
  gload_lds16(gsrc + 64 * 4096, lds_dst + 8192);
}

#define PHASE(CB, P, STAGE, TAIL)            \
  do {                                       \
    phase_lda<P>(aA, smem, CB, a_rd);        \
    if ((P) == 0) phase_ldb(bfr, smem, CB, b_rd); \
    STAGE                                    \
    BARRIER();                               \
    WAIT_LGKM0();                            \
    __builtin_amdgcn_s_setprio(1);           \
    phase_mfma<P>(acc, aA, bfr);             \
    __builtin_amdgcn_s_setprio(0);           \
    TAIL                                     \
    BARRIER();                               \
  } while (0)

__global__ __launch_bounds__(512, 2) void gemm256_8ph(const __bf16* __restrict__ A,
                                                      const __bf16* __restrict__ B,
                                                      const float* __restrict__ bias,
                                                      float* __restrict__ C) {
  __shared__ __align__(16) char smem[131072];

  const int t    = threadIdx.x;          // 0..511
  const int wave = t >> 6;               // 0..7
  const int lane = t & 63;
  const int l16  = lane & 15;
  const int kg   = lane >> 4;            // 0..3
  const int wm   = wave >> 2;            // 0..1 (M half)
  const int wn   = wave & 3;             // 0..3 (N quarter)
  const int bn   = blockIdx.x;           // N/256 = 16
  const int bm   = blockIdx.y;           // M/256 = 32

  // ---- staging source (pre-swizzled): thread t covers row t>>3 (+s*64),
  // chunk c = (t&7) ^ (((t>>5)&1)<<1), 8 elems per chunk.
  const int c8 = (t & 7) ^ (((t >> 5) & 1) << 1);
  const __bf16* gA = A + ((size_t)(bm * 256 + (t >> 3))) * 4096 + c8 * 8;
  const __bf16* gB = B + ((size_t)(bn * 256 + (t >> 3))) * 4096 + c8 * 8;
  char* stw = smem + wave * 1024;        // + lane*16 implicit in global_load_lds

  // ---- ds_read byte offsets (swizzled): row = frag*16 + l16, col = kk*32+kg*8
  const uint32_t sw = ((uint32_t)((l16 >> 2) & 1)) << 5;
  const uint32_t a_rd = (uint32_t)(wm ? A1OFF : A0OFF) + (uint32_t)l16 * 128 +
                        (((uint32_t)kg * 16) ^ sw);
  const uint32_t b_rd = (uint32_t)(wn >= 2 ? B1OFF : B0OFF) +
                        (uint32_t)(wn & 1) * 8192 + (uint32_t)l16 * 128 +
                        (((uint32_t)kg * 16) ^ sw);

  f32x4 acc[8][4];
#pragma unroll
  for (int i = 0; i < 8; ++i)
#pragma unroll
    for (int j = 0; j < 4; ++j) acc[i][j] = (f32x4){0.f, 0.f, 0.f, 0.f};

  bf16x8 aA[2][2];
  bf16x8 bfr[4][2];

  // ---- prologue: tile0 -> buf0 (all), tile1 B -> buf1
  stage_half_tile(gA,             stw + BUF0 + A0OFF);
  stage_half_tile(gA + AH1,       stw + BUF0 + A1OFF);
  stage_half_tile(gB,             stw + BUF0 + B0OFF);
  stage_half_tile(gB + AH1,       stw + BUF0 + B1OFF);
  stage_half_tile(gB + 64,        stw + BUF1 + B0OFF);
  stage_half_tile(gB + AH1 + 64,  stw + BUF1 + B1OFF);
  WAIT_VM4();
  BARRIER();

  // ---- main loop: iter j computes tiles E=2j (buf0), O=2j+1 (buf1)
  for (int j = 0; j < NITER - 1; ++j) {
    const size_t kO  = (size_t)(2 * j + 1) * 64;
    const size_t kE2 = (size_t)(2 * j + 2) * 64;
    const size_t kO2 = (size_t)(2 * j + 3) * 64;
    PHASE(BUF0, 0, stage_half_tile(gA + kO,        stw + BUF1 + A0OFF);, );
    PHASE(BUF0, 1, stage_half_tile(gA + AH1 + kO,  stw + BUF1 + A1OFF);, );
    PHASE(BUF0, 2, stage_half_tile(gB + kE2,       stw + BUF0 + B0OFF);, );
    PHASE(BUF0, 3, stage_half_tile(gB + AH1 + kE2, stw + BUF0 + B1OFF);, WAIT_VM4(););
    PHASE(BUF1, 0, stage_half_tile(gA + kE2,       stw + BUF0 + A0OFF);, );
    PHASE(BUF1, 1, stage_half_tile(gA + AH1 + kE2, stw + BUF0 + A1OFF);, );
    PHASE(BUF1, 2, stage_half_tile(gB + kO2,       stw + BUF1 + B0OFF);, );
    PHASE(BUF1, 3, stage_half_tile(gB + AH1 + kO2, stw + BUF1 + B1OFF);, WAIT_VM4(););
  }
  // ---- last iter (E=62, O=63): no new prefetch except buf1.A <- O
  {
    const size_t kO = (size_t)(2 * (NITER - 1) + 1) * 64;
    PHASE(BUF0, 0, stage_half_tile(gA + kO,       stw + BUF1 + A0OFF);, );
    PHASE(BUF0, 1, stage_half_tile(gA + AH1 + kO, stw + BUF1 + A1OFF);, );
    PHASE(BUF0, 2, ;, );
    PHASE(BUF0, 3, ;, WAIT_VM0(););
    PHASE(BUF1, 0, ;, );
    PHASE(BUF1, 1, ;, );
    PHASE(BUF1, 2, ;, );
    PHASE(BUF1, 3, ;, );
  }

  // ---- epilogue: C/D layout col = lane&15 (n), row = kg*4 + reg (m)
#pragma unroll
  for (int mf = 0; mf < 8; ++mf) {
    const int m0 = bm * 256 + wm * 128 + mf * 16 + kg * 4;
#pragma unroll
    for (int nf = 0; nf < 4; ++nf) {
      const int n = bn * 256 + wn * 64 + nf * 16 + l16;
      const float bv = bias[n];
#pragma unroll
      for (int r = 0; r < 4; ++r)
        C[(size_t)(m0 + r) * N_DIM + n] = acc[mf][nf][r] + bv;
    }
  }
}

// ---------------- fallback: fused naive ----------------
__global__ __launch_bounds__(256) void naive_fused(const float* __restrict__ x,
                                                   const int* __restrict__ q,
                                                   const float* __restrict__ scales,
                                                   const float* __restrict__ bias,
                                                   float* __restrict__ out) {
  __shared__ float xs[K_DIM];
  const int m = blockIdx.y;
  const int n = blockIdx.x * 256 + threadIdx.x;
  for (int k = threadIdx.x; k < K_DIM; k += 256)
    xs[k] = x[(size_t)m * K_DIM + k];
  __syncthreads();

  const int4* q4 = reinterpret_cast<const int4*>(q) + (size_t)n * 512;
  float acc = 0.f, sc = 0.f;
  for (int c = 0; c < 512; ++c) {
    if ((c & 3) == 0) sc = scales[n * 128 + (c >> 2)];
    int4 v = q4[c];
    int b0 = v.x & 0xFF, b1 = v.y & 0xFF, b2 = v.z & 0xFF, b3 = v.w & 0xFF;
    int k = c * 8;
    acc += xs[k + 0] * fp4_to_f32((b0 >> 4) & 15) * sc;
    acc += xs[k + 1] * fp4_to_f32(b0 & 15) * sc;
    acc += xs[k + 2] * fp4_to_f32((b1 >> 4) & 15) * sc;
    acc += xs[k + 3] * fp4_to_f32(b1 & 15) * sc;
    acc += xs[k + 4] * fp4_to_f32((b2 >> 4) & 15) * sc;
    acc += xs[k + 5] * fp4_to_f32(b2 & 15) * sc;
    acc += xs[k + 6] * fp4_to_f32((b3 >> 4) & 15) * sc;
    acc += xs[k + 7] * fp4_to_f32(b3 & 15) * sc;
  }
  out[(size_t)m * N_DIM + n] = acc + bias[n];
}

// ---------------- launch ----------------
extern "C" void kernel_launch(void* const* d_in, const int* in_sizes, int n_in,
                              void* d_out, int out_size, void* d_ws, size_t ws_size,
                              hipStream_t stream) {
  const float* x    = (const float*)d_in[0];
  const int*   q    = (const int*)d_in[1];
  const float* sc   = (const float*)d_in[2];
  const float* bias = (const float*)d_in[3];
  float* out = (float*)d_out;

  const size_t xb_bytes = (size_t)M_DIM * K_DIM * 2;
  const size_t w_bytes  = (size_t)N_DIM * K_DIM * 2;

  if (ws_size >= xb_bytes + w_bytes) {
    uint32_t* xb = (uint32_t*)d_ws;
    uint32_t* W  = (uint32_t*)((char*)d_ws + xb_bytes);

    dequant_w<<<NBLK_W / 256, 256, 0, stream>>>(q, sc, W);
    cvt_x<<<(M_DIM * (size_t)K_DIM / 8) / 256, 256, 0, stream>>>(x, xb);

    dim3 grid(N_DIM / 256, M_DIM / 256);
    gemm256_8ph<<<grid, 512, 0, stream>>>((const __bf16*)xb, (const __bf16*)W, bias, out);
  } else {
    dim3 grid(N_DIM / 256, M_DIM);
    naive_fused<<<grid, 256, 0, stream>>>(x, q, sc, bias, out);
  }
}

// Round 3
// 288.067 us; speedup vs baseline: 1.3028x; 1.0484x over previous
//
#include <hip/hip_runtime.h>
#include <hip/hip_bf16.h>
#include <stdint.h>

// y[b,s,o] = sum_k x[b,s,k] * W[o,k] + bias[o]
// W from packed FP4 (E2M1 nibbles in int32 bytes) * per-32 fp32 scales.
// M = 8192, N = 4096, K = 4096.

#define M_DIM 8192
#define N_DIM 4096
#define K_DIM 4096
#define NBLK_W (N_DIM * K_DIM / 32)

typedef __bf16 bf16x8 __attribute__((ext_vector_type(8)));
typedef float  f32x4  __attribute__((ext_vector_type(4)));

// ---------------- helpers ----------------

__device__ __forceinline__ uint16_t f32_to_bf16_rn(float f) {
  uint32_t u = __float_as_uint(f);
  uint32_t r = (u + 0x7FFFu + ((u >> 16) & 1u)) >> 16;
  return (uint16_t)r;
}
__device__ __forceinline__ uint32_t pack_bf16x2(float e0, float e1) {
  return (uint32_t)f32_to_bf16_rn(e0) | ((uint32_t)f32_to_bf16_rn(e1) << 16);
}
__device__ __forceinline__ float fp4_to_f32(int nib) {
  uint32_t e = (uint32_t)(nib >> 1) & 3u;
  uint32_t m = (uint32_t)nib & 1u;
  uint32_t s = (uint32_t)(nib >> 3) & 1u;
  uint32_t bits = e ? (((126u + e) << 23) | (m << 22)) : (m ? 0x3F000000u : 0u);
  bits |= s << 31;
  return __uint_as_float(bits);
}
__device__ __forceinline__ void gload_lds16(const void* g, void* lds) {
  __builtin_amdgcn_global_load_lds(
      (const __attribute__((address_space(1))) unsigned int*)g,
      (__attribute__((address_space(3))) unsigned int*)lds,
      16, 0, 0);
}

// ---------------- kernel 1: dequant W -> bf16 [N][K] ----------------
__global__ __launch_bounds__(256) void dequant_w(const int* __restrict__ q,
                                                 const float* __restrict__ scales,
                                                 uint32_t* __restrict__ W) {
  int b = blockIdx.x * 256 + threadIdx.x;
  float sc = scales[b];
  const int4* q4 = reinterpret_cast<const int4*>(q) + (size_t)b * 4;
  int4* dst = reinterpret_cast<int4*>(W + (size_t)b * 16);
#pragma unroll
  for (int i = 0; i < 4; ++i) {
    int4 v = q4[i];
    int b0 = v.x & 0xFF, b1 = v.y & 0xFF, b2 = v.z & 0xFF, b3 = v.w & 0xFF;
    uint32_t p0 = pack_bf16x2(fp4_to_f32((b0 >> 4) & 15) * sc, fp4_to_f32(b0 & 15) * sc);
    uint32_t p1 = pack_bf16x2(fp4_to_f32((b1 >> 4) & 15) * sc, fp4_to_f32(b1 & 15) * sc);
    uint32_t p2 = pack_bf16x2(fp4_to_f32((b2 >> 4) & 15) * sc, fp4_to_f32(b2 & 15) * sc);
    uint32_t p3 = pack_bf16x2(fp4_to_f32((b3 >> 4) & 15) * sc, fp4_to_f32(b3 & 15) * sc);
    int4 o; o.x = (int)p0; o.y = (int)p1; o.z = (int)p2; o.w = (int)p3;
    dst[i] = o;
  }
}

// ---------------- kernel 2: cvt x fp32 -> bf16 ----------------
__global__ __launch_bounds__(256) void cvt_x(const float* __restrict__ x,
                                             uint32_t* __restrict__ xb) {
  size_t i = ((size_t)blockIdx.x * 256 + threadIdx.x) * 8;
  float4 a = *reinterpret_cast<const float4*>(x + i);
  float4 c = *reinterpret_cast<const float4*>(x + i + 4);
  int4 o;
  o.x = (int)pack_bf16x2(a.x, a.y);
  o.y = (int)pack_bf16x2(a.z, a.w);
  o.z = (int)pack_bf16x2(c.x, c.y);
  o.w = (int)pack_bf16x2(c.z, c.w);
  *reinterpret_cast<int4*>(xb + i / 2) = o;
}

// ---------------- kernel 3: 256x256 8-phase bf16 GEMM (B^T) ----------------
// C[m][n] = sum_k A[m][k]*B[n][k] + bias[n]
// 512 threads = 8 waves (2 M x 4 N). Per-wave: 128x64 out, acc[8][4] f32x4.
// LDS 128 KiB: 2 buffers x { A0,A1,B0,B1 halves of 128x64 bf16 (16 KiB) }.
// 3-bit row swizzle: phys = logical ^ ((row&7)<<4)  (bank bits [6:4] get
// row bits [2:0]); applied via pre-swizzled global source chunk
// c8 = (t&7) ^ ((t>>3)&7) (linear LDS dest) + swizzled ds_read addresses.
// For MFMA reads: bank group bits = (kk*4+kg) ^ (l16&7) -> 16 same-kg lanes
// spread over all 8 groups -> 2-way (free, m136).

#define BUF0 0
#define BUF1 65536
#define A0OFF 0
#define A1OFF 16384
#define B0OFF 32768
#define B1OFF 49152
#define AH1 (128 * 4096)       // +128 rows (elements)
#define NITER 32               // 64 K-tiles, 2 per iter

#define BARRIER()   asm volatile("s_barrier" ::: "memory")
#define WAIT_LGKM0() do { asm volatile("s_waitcnt lgkmcnt(0)" ::: "memory"); \
                          __builtin_amdgcn_sched_barrier(0); } while (0)
#define WAIT_VM4()  asm volatile("s_waitcnt vmcnt(4)" ::: "memory")
#define WAIT_VM0()  asm volatile("s_waitcnt vmcnt(0)" ::: "memory")

// reads A frags 2P, 2P+1; kk=1 chunk is addr ^ 64 (bit 6 is in swizzle field)
template <int P>
__device__ __forceinline__ void phase_lda(bf16x8 (&aA)[2][2], const char* sm,
                                          int cb, uint32_t a_rd) {
  const uint32_t r0 = a_rd + (2 * P) * 2048;
  const uint32_t r1 = a_rd + (2 * P + 1) * 2048;
  aA[0][0] = *(const bf16x8*)(sm + cb + r0);
  aA[0][1] = *(const bf16x8*)(sm + cb + (r0 ^ 64));
  aA[1][0] = *(const bf16x8*)(sm + cb + r1);
  aA[1][1] = *(const bf16x8*)(sm + cb + (r1 ^ 64));
}

__device__ __forceinline__ void phase_ldb(bf16x8 (&bfr)[4][2], const char* sm,
                                          int cb, uint32_t b_rd) {
#pragma unroll
  for (int nf = 0; nf < 4; ++nf) {
    const uint32_t r = b_rd + nf * 2048;
    bfr[nf][0] = *(const bf16x8*)(sm + cb + r);
    bfr[nf][1] = *(const bf16x8*)(sm + cb + (r ^ 64));
  }
}

template <int P>
__device__ __forceinline__ void phase_mfma(f32x4 (&acc)[8][4],
                                           const bf16x8 (&aA)[2][2],
                                           const bf16x8 (&bfr)[4][2]) {
#pragma unroll
  for (int nf = 0; nf < 4; ++nf)
#pragma unroll
    for (int kk = 0; kk < 2; ++kk) {
      acc[2 * P][nf] = __builtin_amdgcn_mfma_f32_16x16x32_bf16(
          aA[0][kk], bfr[nf][kk], acc[2 * P][nf], 0, 0, 0);
      acc[2 * P + 1][nf] = __builtin_amdgcn_mfma_f32_16x16x32_bf16(
          aA[1][kk], bfr[nf][kk], acc[2 * P + 1][nf], 0, 0, 0);
    }
}

// stage one 128x64 half-tile: 2 x global_load_lds (s=0: rows 0-63, s=1: 64-127)
__device__ __forceinline__ void stage_half_tile(const __bf16* gsrc, char* lds_dst) {
  gload_lds16(gsrc, lds_dst);
  gload_lds16(gsrc + 64 * 4096, lds_dst + 8192);
}

#define PHASE(CB, P, STAGE, TAIL)            \
  do {                                       \
    phase_lda<P>(aA, smem, CB, a_rd);        \
    if ((P) == 0) phase_ldb(bfr, smem, CB, b_rd); \
    STAGE                                    \
    BARRIER();                               \
    WAIT_LGKM0();                            \
    __builtin_amdgcn_s_setprio(1);           \
    phase_mfma<P>(acc, aA, bfr);             \
    __builtin_amdgcn_s_setprio(0);           \
    TAIL                                     \
    BARRIER();                               \
  } while (0)

__global__ __launch_bounds__(512, 2) void gemm256_8ph(const __bf16* __restrict__ A,
                                                      const __bf16* __restrict__ B,
                                                      const float* __restrict__ bias,
                                                      float* __restrict__ C) {
  __shared__ __align__(16) char smem[131072];

  const int t    = threadIdx.x;          // 0..511
  const int wave = t >> 6;               // 0..7
  const int lane = t & 63;
  const int l16  = lane & 15;
  const int kg   = lane >> 4;            // 0..3
  const int wm   = wave >> 2;            // 0..1 (M half)
  const int wn   = wave & 3;             // 0..3 (N quarter)
  const int bn   = blockIdx.x;           // N/256 = 16
  const int bm   = blockIdx.y;           // M/256 = 32

  // ---- staging source (pre-swizzled): thread t covers row t>>3 (+s*64),
  // chunk c8 = (t&7) ^ ((t>>3)&7)  (inverse of the 3-bit row swizzle)
  const int c8 = (t & 7) ^ ((t >> 3) & 7);
  const __bf16* gA = A + ((size_t)(bm * 256 + (t >> 3))) * 4096 + c8 * 8;
  const __bf16* gB = B + ((size_t)(bn * 256 + (t >> 3))) * 4096 + c8 * 8;
  char* stw = smem + wave * 1024;        // + lane*16 implicit in global_load_lds

  // ---- ds_read byte offsets (swizzled): row = frag*16 + l16,
  // chunk bits [6:4] = kg ^ (l16&7); kk half via ^64 at use site
  const uint32_t ca = ((uint32_t)(kg ^ (l16 & 7))) << 4;
  const uint32_t a_rd = (uint32_t)(wm ? A1OFF : A0OFF) + (uint32_t)l16 * 128 + ca;
  const uint32_t b_rd = (uint32_t)(wn >= 2 ? B1OFF : B0OFF) +
                        (uint32_t)(wn & 1) * 8192 + (uint32_t)l16 * 128 + ca;

  f32x4 acc[8][4];
#pragma unroll
  for (int i = 0; i < 8; ++i)
#pragma unroll
    for (int j = 0; j < 4; ++j) acc[i][j] = (f32x4){0.f, 0.f, 0.f, 0.f};

  bf16x8 aA[2][2];
  bf16x8 bfr[4][2];

  // ---- prologue: tile0 -> buf0 (all), tile1 B -> buf1
  stage_half_tile(gA,             stw + BUF0 + A0OFF);
  stage_half_tile(gA + AH1,       stw + BUF0 + A1OFF);
  stage_half_tile(gB,             stw + BUF0 + B0OFF);
  stage_half_tile(gB + AH1,       stw + BUF0 + B1OFF);
  stage_half_tile(gB + 64,        stw + BUF1 + B0OFF);
  stage_half_tile(gB + AH1 + 64,  stw + BUF1 + B1OFF);
  WAIT_VM4();
  BARRIER();

  // ---- main loop: iter j computes tiles E=2j (buf0), O=2j+1 (buf1)
  for (int j = 0; j < NITER - 1; ++j) {
    const size_t kO  = (size_t)(2 * j + 1) * 64;
    const size_t kE2 = (size_t)(2 * j + 2) * 64;
    const size_t kO2 = (size_t)(2 * j + 3) * 64;
    PHASE(BUF0, 0, stage_half_tile(gA + kO,        stw + BUF1 + A0OFF);, );
    PHASE(BUF0, 1, stage_half_tile(gA + AH1 + kO,  stw + BUF1 + A1OFF);, );
    PHASE(BUF0, 2, stage_half_tile(gB + kE2,       stw + BUF0 + B0OFF);, );
    PHASE(BUF0, 3, stage_half_tile(gB + AH1 + kE2, stw + BUF0 + B1OFF);, WAIT_VM4(););
    PHASE(BUF1, 0, stage_half_tile(gA + kE2,       stw + BUF0 + A0OFF);, );
    PHASE(BUF1, 1, stage_half_tile(gA + AH1 + kE2, stw + BUF0 + A1OFF);, );
    PHASE(BUF1, 2, stage_half_tile(gB + kO2,       stw + BUF1 + B0OFF);, );
    PHASE(BUF1, 3, stage_half_tile(gB + AH1 + kO2, stw + BUF1 + B1OFF);, WAIT_VM4(););
  }
  // ---- last iter (E=62, O=63): no new prefetch except buf1.A <- O
  {
    const size_t kO = (size_t)(2 * (NITER - 1) + 1) * 64;
    PHASE(BUF0, 0, stage_half_tile(gA + kO,       stw + BUF1 + A0OFF);, );
    PHASE(BUF0, 1, stage_half_tile(gA + AH1 + kO, stw + BUF1 + A1OFF);, );
    PHASE(BUF0, 2, ;, );
    PHASE(BUF0, 3, ;, WAIT_VM0(););
    PHASE(BUF1, 0, ;, );
    PHASE(BUF1, 1, ;, );
    PHASE(BUF1, 2, ;, );
    PHASE(BUF1, 3, ;, );
  }

  // ---- epilogue: C/D layout col = lane&15 (n), row = kg*4 + reg (m)
#pragma unroll
  for (int mf = 0; mf < 8; ++mf) {
    const int m0 = bm * 256 + wm * 128 + mf * 16 + kg * 4;
#pragma unroll
    for (int nf = 0; nf < 4; ++nf) {
      const int n = bn * 256 + wn * 64 + nf * 16 + l16;
      const float bv = bias[n];
#pragma unroll
      for (int r = 0; r < 4; ++r)
        C[(size_t)(m0 + r) * N_DIM + n] = acc[mf][nf][r] + bv;
    }
  }
}

// ---------------- fallback: fused naive ----------------
__global__ __launch_bounds__(256) void naive_fused(const float* __restrict__ x,
                                                   const int* __restrict__ q,
                                                   const float* __restrict__ scales,
                                                   const float* __restrict__ bias,
                                                   float* __restrict__ out) {
  __shared__ float xs[K_DIM];
  const int m = blockIdx.y;
  const int n = blockIdx.x * 256 + threadIdx.x;
  for (int k = threadIdx.x; k < K_DIM; k += 256)
    xs[k] = x[(size_t)m * K_DIM + k];
  __syncthreads();

  const int4* q4 = reinterpret_cast<const int4*>(q) + (size_t)n * 512;
  float acc = 0.f, sc = 0.f;
  for (int c = 0; c < 512; ++c) {
    if ((c & 3) == 0) sc = scales[n * 128 + (c >> 2)];
    int4 v = q4[c];
    int b0 = v.x & 0xFF, b1 = v.y & 0xFF, b2 = v.z & 0xFF, b3 = v.w & 0xFF;
    int k = c * 8;
    acc += xs[k + 0] * fp4_to_f32((b0 >> 4) & 15) * sc;
    acc += xs[k + 1] * fp4_to_f32(b0 & 15) * sc;
    acc += xs[k + 2] * fp4_to_f32((b1 >> 4) & 15) * sc;
    acc += xs[k + 3] * fp4_to_f32(b1 & 15) * sc;
    acc += xs[k + 4] * fp4_to_f32((b2 >> 4) & 15) * sc;
    acc += xs[k + 5] * fp4_to_f32(b2 & 15) * sc;
    acc += xs[k + 6] * fp4_to_f32((b3 >> 4) & 15) * sc;
    acc += xs[k + 7] * fp4_to_f32(b3 & 15) * sc;
  }
  out[(size_t)m * N_DIM + n] = acc + bias[n];
}

// ---------------- launch ----------------
extern "C" void kernel_launch(void* const* d_in, const int* in_sizes, int n_in,
                              void* d_out, int out_size, void* d_ws, size_t ws_size,
                              hipStream_t stream) {
  const float* x    = (const float*)d_in[0];
  const int*   q    = (const int*)d_in[1];
  const float* sc   = (const float*)d_in[2];
  const float* bias = (const float*)d_in[3];
  float* out = (float*)d_out;

  const size_t xb_bytes = (size_t)M_DIM * K_DIM * 2;
  const size_t w_bytes  = (size_t)N_DIM * K_DIM * 2;

  if (ws_size >= xb_bytes + w_bytes) {
    uint32_t* xb = (uint32_t*)d_ws;
    uint32_t* W  = (uint32_t*)((char*)d_ws + xb_bytes);

    dequant_w<<<NBLK_W / 256, 256, 0, stream>>>(q, sc, W);
    cvt_x<<<(M_DIM * (size_t)K_DIM / 8) / 256, 256, 0, stream>>>(x, xb);

    dim3 grid(N_DIM / 256, M_DIM / 256);
    gemm256_8ph<<<grid, 512, 0, stream>>>((const __bf16*)xb, (const __bf16*)W, bias, out);
  } else {
    dim3 grid(N_DIM / 256, M_DIM);
    naive_fused<<<grid, 256, 0, stream>>>(x, q, sc, bias, out);
  }
}

// Round 4
// 284.891 us; speedup vs baseline: 1.3173x; 1.0111x over previous
//
#include <hip/hip_runtime.h>
#include <hip/hip_bf16.h>
#include <stdint.h>

// y[b,s,o] = sum_k x[b,s,k] * W[o,k] + bias[o]
// W from packed FP4 (E2M1 nibbles in int32 bytes) * per-32 fp32 scales.
// M = 8192, N = 4096, K = 4096.

#define M_DIM 8192
#define N_DIM 4096
#define K_DIM 4096
#define NBLK_W (N_DIM * K_DIM / 32)

typedef __bf16 bf16x8 __attribute__((ext_vector_type(8)));
typedef float  f32x4  __attribute__((ext_vector_type(4)));

// ---------------- helpers ----------------

__device__ __forceinline__ uint16_t f32_to_bf16_rn(float f) {
  uint32_t u = __float_as_uint(f);
  uint32_t r = (u + 0x7FFFu + ((u >> 16) & 1u)) >> 16;
  return (uint16_t)r;
}
__device__ __forceinline__ uint32_t pack_bf16x2(float e0, float e1) {
  return (uint32_t)f32_to_bf16_rn(e0) | ((uint32_t)f32_to_bf16_rn(e1) << 16);
}
__device__ __forceinline__ float fp4_to_f32(int nib) {
  uint32_t e = (uint32_t)(nib >> 1) & 3u;
  uint32_t m = (uint32_t)nib & 1u;
  uint32_t s = (uint32_t)(nib >> 3) & 1u;
  uint32_t bits = e ? (((126u + e) << 23) | (m << 22)) : (m ? 0x3F000000u : 0u);
  bits |= s << 31;
  return __uint_as_float(bits);
}
__device__ __forceinline__ void gload_lds16(const void* g, void* lds) {
  __builtin_amdgcn_global_load_lds(
      (const __attribute__((address_space(1))) unsigned int*)g,
      (__attribute__((address_space(3))) unsigned int*)lds,
      16, 0, 0);
}

// ---------------- kernel 1: dequant W -> bf16 [N][K] ----------------
__global__ __launch_bounds__(256) void dequant_w(const int* __restrict__ q,
                                                 const float* __restrict__ scales,
                                                 uint32_t* __restrict__ W) {
  int b = blockIdx.x * 256 + threadIdx.x;
  float sc = scales[b];
  const int4* q4 = reinterpret_cast<const int4*>(q) + (size_t)b * 4;
  int4* dst = reinterpret_cast<int4*>(W + (size_t)b * 16);
#pragma unroll
  for (int i = 0; i < 4; ++i) {
    int4 v = q4[i];
    int b0 = v.x & 0xFF, b1 = v.y & 0xFF, b2 = v.z & 0xFF, b3 = v.w & 0xFF;
    uint32_t p0 = pack_bf16x2(fp4_to_f32((b0 >> 4) & 15) * sc, fp4_to_f32(b0 & 15) * sc);
    uint32_t p1 = pack_bf16x2(fp4_to_f32((b1 >> 4) & 15) * sc, fp4_to_f32(b1 & 15) * sc);
    uint32_t p2 = pack_bf16x2(fp4_to_f32((b2 >> 4) & 15) * sc, fp4_to_f32(b2 & 15) * sc);
    uint32_t p3 = pack_bf16x2(fp4_to_f32((b3 >> 4) & 15) * sc, fp4_to_f32(b3 & 15) * sc);
    int4 o; o.x = (int)p0; o.y = (int)p1; o.z = (int)p2; o.w = (int)p3;
    dst[i] = o;
  }
}

// ---------------- kernel 2: cvt x fp32 -> bf16 ----------------
__global__ __launch_bounds__(256) void cvt_x(const float* __restrict__ x,
                                             uint32_t* __restrict__ xb) {
  size_t i = ((size_t)blockIdx.x * 256 + threadIdx.x) * 8;
  float4 a = *reinterpret_cast<const float4*>(x + i);
  float4 c = *reinterpret_cast<const float4*>(x + i + 4);
  int4 o;
  o.x = (int)pack_bf16x2(a.x, a.y);
  o.y = (int)pack_bf16x2(a.z, a.w);
  o.z = (int)pack_bf16x2(c.x, c.y);
  o.w = (int)pack_bf16x2(c.z, c.w);
  *reinterpret_cast<int4*>(xb + i / 2) = o;
}

// ---------------- kernel 3: 256x256 8-phase bf16 GEMM (B^T) ----------------
// C[m][n] = sum_k A[m][k]*B[n][k] + bias[n]
// 512 threads = 8 waves (2 M x 4 N). Per-wave: 128x64 out, acc[8][4] f32x4.
// LDS 128 KiB: 2 buffers x { A0,A1,B0,B1 halves of 128x64 bf16 (16 KiB) }.
// 3-bit row swizzle: phys = logical ^ ((row&7)<<4); pre-swizzled global
// source chunk c8 = (t&7) ^ ((t>>3)&7) (linear LDS dest) + swizzled ds_read.
// T1: bijective XCD-aware block swizzle (nwg=512 % 8 == 0) so each XCD owns
// 4 consecutive bm-rows x all bn -> A-panels fetched once, B L3-resident.

#define BUF0 0
#define BUF1 65536
#define A0OFF 0
#define A1OFF 16384
#define B0OFF 32768
#define B1OFF 49152
#define AH1 (128 * 4096)       // +128 rows (elements)
#define NITER 32               // 64 K-tiles, 2 per iter

#define BARRIER()   asm volatile("s_barrier" ::: "memory")
#define WAIT_LGKM0() do { asm volatile("s_waitcnt lgkmcnt(0)" ::: "memory"); \
                          __builtin_amdgcn_sched_barrier(0); } while (0)
#define WAIT_VM4()  asm volatile("s_waitcnt vmcnt(4)" ::: "memory")
#define WAIT_VM0()  asm volatile("s_waitcnt vmcnt(0)" ::: "memory")

// reads A frags 2P, 2P+1; kk=1 chunk is addr ^ 64 (bit 6 is in swizzle field)
template <int P>
__device__ __forceinline__ void phase_lda(bf16x8 (&aA)[2][2], const char* sm,
                                          int cb, uint32_t a_rd) {
  const uint32_t r0 = a_rd + (2 * P) * 2048;
  const uint32_t r1 = a_rd + (2 * P + 1) * 2048;
  aA[0][0] = *(const bf16x8*)(sm + cb + r0);
  aA[0][1] = *(const bf16x8*)(sm + cb + (r0 ^ 64));
  aA[1][0] = *(const bf16x8*)(sm + cb + r1);
  aA[1][1] = *(const bf16x8*)(sm + cb + (r1 ^ 64));
}

__device__ __forceinline__ void phase_ldb(bf16x8 (&bfr)[4][2], const char* sm,
                                          int cb, uint32_t b_rd) {
#pragma unroll
  for (int nf = 0; nf < 4; ++nf) {
    const uint32_t r = b_rd + nf * 2048;
    bfr[nf][0] = *(const bf16x8*)(sm + cb + r);
    bfr[nf][1] = *(const bf16x8*)(sm + cb + (r ^ 64));
  }
}

template <int P>
__device__ __forceinline__ void phase_mfma(f32x4 (&acc)[8][4],
                                           const bf16x8 (&aA)[2][2],
                                           const bf16x8 (&bfr)[4][2]) {
#pragma unroll
  for (int nf = 0; nf < 4; ++nf)
#pragma unroll
    for (int kk = 0; kk < 2; ++kk) {
      acc[2 * P][nf] = __builtin_amdgcn_mfma_f32_16x16x32_bf16(
          aA[0][kk], bfr[nf][kk], acc[2 * P][nf], 0, 0, 0);
      acc[2 * P + 1][nf] = __builtin_amdgcn_mfma_f32_16x16x32_bf16(
          aA[1][kk], bfr[nf][kk], acc[2 * P + 1][nf], 0, 0, 0);
    }
}

// stage one 128x64 half-tile: 2 x global_load_lds (s=0: rows 0-63, s=1: 64-127)
__device__ __forceinline__ void stage_half_tile(const __bf16* gsrc, char* lds_dst) {
  gload_lds16(gsrc, lds_dst);
  gload_lds16(gsrc + 64 * 4096, lds_dst + 8192);
}

#define PHASE(CB, P, STAGE, TAIL)            \
  do {                                       \
    phase_lda<P>(aA, smem, CB, a_rd);        \
    if ((P) == 0) phase_ldb(bfr, smem, CB, b_rd); \
    STAGE                                    \
    BARRIER();                               \
    WAIT_LGKM0();                            \
    __builtin_amdgcn_s_setprio(1);           \
    phase_mfma<P>(acc, aA, bfr);             \
    __builtin_amdgcn_s_setprio(0);           \
    TAIL                                     \
    BARRIER();                               \
  } while (0)

__global__ __launch_bounds__(512, 2) void gemm256_8ph(const __bf16* __restrict__ A,
                                                      const __bf16* __restrict__ B,
                                                      const float* __restrict__ bias,
                                                      float* __restrict__ C) {
  __shared__ __align__(16) char smem[131072];

  const int t    = threadIdx.x;          // 0..511
  const int wave = t >> 6;               // 0..7
  const int lane = t & 63;
  const int l16  = lane & 15;
  const int kg   = lane >> 4;            // 0..3
  const int wm   = wave >> 2;            // 0..1 (M half)
  const int wn   = wave & 3;             // 0..3 (N quarter)

  // ---- T1: XCD-aware bijective block swizzle. nwg = 512 = 8 XCDs x 64.
  // swz consecutive within a 64-chunk -> same XCD -> 4 bm-rows x 16 bn.
  const int orig = blockIdx.x;                     // 0..511
  const int swz  = (orig & 7) * 64 + (orig >> 3);
  const int bn   = swz & 15;                       // N/256 = 16 (fastest)
  const int bm   = swz >> 4;                       // M/256 = 32

  // ---- staging source (pre-swizzled): thread t covers row t>>3 (+s*64),
  // chunk c8 = (t&7) ^ ((t>>3)&7)  (inverse of the 3-bit row swizzle)
  const int c8 = (t & 7) ^ ((t >> 3) & 7);
  const __bf16* gA = A + ((size_t)(bm * 256 + (t >> 3))) * 4096 + c8 * 8;
  const __bf16* gB = B + ((size_t)(bn * 256 + (t >> 3))) * 4096 + c8 * 8;
  char* stw = smem + wave * 1024;        // + lane*16 implicit in global_load_lds

  // ---- ds_read byte offsets (swizzled): row = frag*16 + l16,
  // chunk bits [6:4] = kg ^ (l16&7); kk half via ^64 at use site
  const uint32_t ca = ((uint32_t)(kg ^ (l16 & 7))) << 4;
  const uint32_t a_rd = (uint32_t)(wm ? A1OFF : A0OFF) + (uint32_t)l16 * 128 + ca;
  const uint32_t b_rd = (uint32_t)(wn >= 2 ? B1OFF : B0OFF) +
                        (uint32_t)(wn & 1) * 8192 + (uint32_t)l16 * 128 + ca;

  f32x4 acc[8][4];
#pragma unroll
  for (int i = 0; i < 8; ++i)
#pragma unroll
    for (int j = 0; j < 4; ++j) acc[i][j] = (f32x4){0.f, 0.f, 0.f, 0.f};

  bf16x8 aA[2][2];
  bf16x8 bfr[4][2];

  // ---- prologue: tile0 -> buf0 (all), tile1 B -> buf1
  stage_half_tile(gA,             stw + BUF0 + A0OFF);
  stage_half_tile(gA + AH1,       stw + BUF0 + A1OFF);
  stage_half_tile(gB,             stw + BUF0 + B0OFF);
  stage_half_tile(gB + AH1,       stw + BUF0 + B1OFF);
  stage_half_tile(gB + 64,        stw + BUF1 + B0OFF);
  stage_half_tile(gB + AH1 + 64,  stw + BUF1 + B1OFF);
  WAIT_VM4();
  BARRIER();

  // ---- main loop: iter j computes tiles E=2j (buf0), O=2j+1 (buf1)
  for (int j = 0; j < NITER - 1; ++j) {
    const size_t kO  = (size_t)(2 * j + 1) * 64;
    const size_t kE2 = (size_t)(2 * j + 2) * 64;
    const size_t kO2 = (size_t)(2 * j + 3) * 64;
    PHASE(BUF0, 0, stage_half_tile(gA + kO,        stw + BUF1 + A0OFF);, );
    PHASE(BUF0, 1, stage_half_tile(gA + AH1 + kO,  stw + BUF1 + A1OFF);, );
    PHASE(BUF0, 2, stage_half_tile(gB + kE2,       stw + BUF0 + B0OFF);, );
    PHASE(BUF0, 3, stage_half_tile(gB + AH1 + kE2, stw + BUF0 + B1OFF);, WAIT_VM4(););
    PHASE(BUF1, 0, stage_half_tile(gA + kE2,       stw + BUF0 + A0OFF);, );
    PHASE(BUF1, 1, stage_half_tile(gA + AH1 + kE2, stw + BUF0 + A1OFF);, );
    PHASE(BUF1, 2, stage_half_tile(gB + kO2,       stw + BUF1 + B0OFF);, );
    PHASE(BUF1, 3, stage_half_tile(gB + AH1 + kO2, stw + BUF1 + B1OFF);, WAIT_VM4(););
  }
  // ---- last iter (E=62, O=63): no new prefetch except buf1.A <- O
  {
    const size_t kO = (size_t)(2 * (NITER - 1) + 1) * 64;
    PHASE(BUF0, 0, stage_half_tile(gA + kO,       stw + BUF1 + A0OFF);, );
    PHASE(BUF0, 1, stage_half_tile(gA + AH1 + kO, stw + BUF1 + A1OFF);, );
    PHASE(BUF0, 2, ;, );
    PHASE(BUF0, 3, ;, WAIT_VM0(););
    PHASE(BUF1, 0, ;, );
    PHASE(BUF1, 1, ;, );
    PHASE(BUF1, 2, ;, );
    PHASE(BUF1, 3, ;, );
  }

  // ---- epilogue: C/D layout col = lane&15 (n), row = kg*4 + reg (m)
#pragma unroll
  for (int mf = 0; mf < 8; ++mf) {
    const int m0 = bm * 256 + wm * 128 + mf * 16 + kg * 4;
#pragma unroll
    for (int nf = 0; nf < 4; ++nf) {
      const int n = bn * 256 + wn * 64 + nf * 16 + l16;
      const float bv = bias[n];
#pragma unroll
      for (int r = 0; r < 4; ++r)
        C[(size_t)(m0 + r) * N_DIM + n] = acc[mf][nf][r] + bv;
    }
  }
}

// ---------------- fallback: fused naive ----------------
__global__ __launch_bounds__(256) void naive_fused(const float* __restrict__ x,
                                                   const int* __restrict__ q,
                                                   const float* __restrict__ scales,
                                                   const float* __restrict__ bias,
                                                   float* __restrict__ out) {
  __shared__ float xs[K_DIM];
  const int m = blockIdx.y;
  const int n = blockIdx.x * 256 + threadIdx.x;
  for (int k = threadIdx.x; k < K_DIM; k += 256)
    xs[k] = x[(size_t)m * K_DIM + k];
  __syncthreads();

  const int4* q4 = reinterpret_cast<const int4*>(q) + (size_t)n * 512;
  float acc = 0.f, sc = 0.f;
  for (int c = 0; c < 512; ++c) {
    if ((c & 3) == 0) sc = scales[n * 128 + (c >> 2)];
    int4 v = q4[c];
    int b0 = v.x & 0xFF, b1 = v.y & 0xFF, b2 = v.z & 0xFF, b3 = v.w & 0xFF;
    int k = c * 8;
    acc += xs[k + 0] * fp4_to_f32((b0 >> 4) & 15) * sc;
    acc += xs[k + 1] * fp4_to_f32(b0 & 15) * sc;
    acc += xs[k + 2] * fp4_to_f32((b1 >> 4) & 15) * sc;
    acc += xs[k + 3] * fp4_to_f32(b1 & 15) * sc;
    acc += xs[k + 4] * fp4_to_f32((b2 >> 4) & 15) * sc;
    acc += xs[k + 5] * fp4_to_f32(b2 & 15) * sc;
    acc += xs[k + 6] * fp4_to_f32((b3 >> 4) & 15) * sc;
    acc += xs[k + 7] * fp4_to_f32(b3 & 15) * sc;
  }
  out[(size_t)m * N_DIM + n] = acc + bias[n];
}

// ---------------- launch ----------------
extern "C" void kernel_launch(void* const* d_in, const int* in_sizes, int n_in,
                              void* d_out, int out_size, void* d_ws, size_t ws_size,
                              hipStream_t stream) {
  const float* x    = (const float*)d_in[0];
  const int*   q    = (const int*)d_in[1];
  const float* sc   = (const float*)d_in[2];
  const float* bias = (const float*)d_in[3];
  float* out = (float*)d_out;

  const size_t xb_bytes = (size_t)M_DIM * K_DIM * 2;
  const size_t w_bytes  = (size_t)N_DIM * K_DIM * 2;

  if (ws_size >= xb_bytes + w_bytes) {
    uint32_t* xb = (uint32_t*)d_ws;
    uint32_t* W  = (uint32_t*)((char*)d_ws + xb_bytes);

    dequant_w<<<NBLK_W / 256, 256, 0, stream>>>(q, sc, W);
    cvt_x<<<(M_DIM * (size_t)K_DIM / 8) / 256, 256, 0, stream>>>(x, xb);

    gemm256_8ph<<<dim3(512), 512, 0, stream>>>((const __bf16*)xb, (const __bf16*)W, bias, out);
  } else {
    dim3 grid(N_DIM / 256, M_DIM);
    naive_fused<<<grid, 256, 0, stream>>>(x, q, sc, bias, out);
  }
}

// Round 5
// 281.972 us; speedup vs baseline: 1.3309x; 1.0104x over previous
//
#include <hip/hip_runtime.h>
#include <hip/hip_bf16.h>
#include <stdint.h>

// y[b,s,o] = sum_k x[b,s,k] * W[o,k] + bias[o]
// W from packed FP4 (E2M1 nibbles in int32 bytes) * per-32 fp32 scales.
// M = 8192, N = 4096, K = 4096.

#define M_DIM 8192
#define N_DIM 4096
#define K_DIM 4096
#define NBLK_W (N_DIM * K_DIM / 32)

typedef __bf16 bf16x8 __attribute__((ext_vector_type(8)));
typedef float  f32x4  __attribute__((ext_vector_type(4)));

// ---------------- helpers ----------------

__device__ __forceinline__ uint16_t f32_to_bf16_rn(float f) {
  uint32_t u = __float_as_uint(f);
  uint32_t r = (u + 0x7FFFu + ((u >> 16) & 1u)) >> 16;
  return (uint16_t)r;
}
__device__ __forceinline__ uint32_t pack_bf16x2(float e0, float e1) {
  return (uint32_t)f32_to_bf16_rn(e0) | ((uint32_t)f32_to_bf16_rn(e1) << 16);
}
__device__ __forceinline__ float fp4_to_f32(int nib) {
  uint32_t e = (uint32_t)(nib >> 1) & 3u;
  uint32_t m = (uint32_t)nib & 1u;
  uint32_t s = (uint32_t)(nib >> 3) & 1u;
  uint32_t bits = e ? (((126u + e) << 23) | (m << 22)) : (m ? 0x3F000000u : 0u);
  bits |= s << 31;
  return __uint_as_float(bits);
}
__device__ __forceinline__ void gload_lds16(const void* g, void* lds) {
  __builtin_amdgcn_global_load_lds(
      (const __attribute__((address_space(1))) unsigned int*)g,
      (__attribute__((address_space(3))) unsigned int*)lds,
      16, 0, 0);
}

// ---------------- kernel 1: dequant W -> bf16 [N][K] ----------------
__global__ __launch_bounds__(256) void dequant_w(const int* __restrict__ q,
                                                 const float* __restrict__ scales,
                                                 uint32_t* __restrict__ W) {
  int b = blockIdx.x * 256 + threadIdx.x;
  float sc = scales[b];
  const int4* q4 = reinterpret_cast<const int4*>(q) + (size_t)b * 4;
  int4* dst = reinterpret_cast<int4*>(W + (size_t)b * 16);
#pragma unroll
  for (int i = 0; i < 4; ++i) {
    int4 v = q4[i];
    int b0 = v.x & 0xFF, b1 = v.y & 0xFF, b2 = v.z & 0xFF, b3 = v.w & 0xFF;
    uint32_t p0 = pack_bf16x2(fp4_to_f32((b0 >> 4) & 15) * sc, fp4_to_f32(b0 & 15) * sc);
    uint32_t p1 = pack_bf16x2(fp4_to_f32((b1 >> 4) & 15) * sc, fp4_to_f32(b1 & 15) * sc);
    uint32_t p2 = pack_bf16x2(fp4_to_f32((b2 >> 4) & 15) * sc, fp4_to_f32(b2 & 15) * sc);
    uint32_t p3 = pack_bf16x2(fp4_to_f32((b3 >> 4) & 15) * sc, fp4_to_f32(b3 & 15) * sc);
    int4 o; o.x = (int)p0; o.y = (int)p1; o.z = (int)p2; o.w = (int)p3;
    dst[i] = o;
  }
}

// ---------------- kernel 2: cvt x fp32 -> bf16 ----------------
__global__ __launch_bounds__(256) void cvt_x(const float* __restrict__ x,
                                             uint32_t* __restrict__ xb) {
  size_t i = ((size_t)blockIdx.x * 256 + threadIdx.x) * 8;
  float4 a = *reinterpret_cast<const float4*>(x + i);
  float4 c = *reinterpret_cast<const float4*>(x + i + 4);
  int4 o;
  o.x = (int)pack_bf16x2(a.x, a.y);
  o.y = (int)pack_bf16x2(a.z, a.w);
  o.z = (int)pack_bf16x2(c.x, c.y);
  o.w = (int)pack_bf16x2(c.z, c.w);
  *reinterpret_cast<int4*>(xb + i / 2) = o;
}

// ---------------- kernel 3: 256x256 8-phase pipelined bf16 GEMM (B^T) ----
// C[m][n] = sum_k A[m][k]*B[n][k] + bias[n]
// 512 threads = 8 waves (2M x 4N). Per-wave 128x64 out, acc[8][4] f32x4.
// LDS 128 KiB: 2 bufs x {A0,A1,B0,B1 halves 128x64 bf16}.
// 3-bit row swizzle (bank bits [6:4] ^= row bits [2:0]); pre-swizzled
// global source (linear gload_lds dest) + swizzled ds_read addrs.
// REGISTER PIPELINING: phase P's MFMA uses A-frags read at P-1 (aA[2] sets
// alternate); P issues P+1's 4 A-reads before its MFMA so they drain under
// it. B (8 reads) issued at owning phase head with counted lgkmcnt(4).
// ONE barrier per phase. Stages in tail slots; counted vmcnt(4)@P2,
// vmcnt(6)@P6 (never 0 in steady loop).

#define BUF0 0
#define BUF1 65536
#define A0OFF 0
#define A1OFF 16384
#define B0OFF 32768
#define B1OFF 49152
#define AH1 (128 * 4096)       // +128 rows (elements)
#define NITER 32               // 64 K-tiles, 2 per iter

#define BARRIER()   asm volatile("s_barrier" ::: "memory")
#define WAIT_LGKM0() do { asm volatile("s_waitcnt lgkmcnt(0)" ::: "memory"); \
                          __builtin_amdgcn_sched_barrier(0); } while (0)
#define LGKM4()     do { asm volatile("s_waitcnt lgkmcnt(4)" ::: "memory"); \
                          __builtin_amdgcn_sched_barrier(0); } while (0)
#define WAIT_VM6()  asm volatile("s_waitcnt vmcnt(6)" ::: "memory")
#define WAIT_VM4()  asm volatile("s_waitcnt vmcnt(4)" ::: "memory")
#define WAIT_VM0()  asm volatile("s_waitcnt vmcnt(0)" ::: "memory")
#define PRIO1()     __builtin_amdgcn_s_setprio(1)
#define PRIO0()     __builtin_amdgcn_s_setprio(0)

// read A frags F, F+1 from buf CB into set SET (kk=1 chunk = addr ^ 64)
#define LDA2(SET, CB, F) do {                                      \
    const uint32_t r0_ = a_rd + (F) * 2048;                        \
    const uint32_t r1_ = a_rd + ((F) + 1) * 2048;                  \
    aA[SET][0][0] = *(const bf16x8*)(smem + (CB) + r0_);           \
    aA[SET][0][1] = *(const bf16x8*)(smem + (CB) + (r0_ ^ 64));    \
    aA[SET][1][0] = *(const bf16x8*)(smem + (CB) + r1_);           \
    aA[SET][1][1] = *(const bf16x8*)(smem + (CB) + (r1_ ^ 64));    \
  } while (0)

// read all 4 B frags (x2 kk) from buf CB
#define LDB(CB) do {                                               \
    _Pragma("unroll")                                              \
    for (int nf_ = 0; nf_ < 4; ++nf_) {                            \
      const uint32_t r_ = b_rd + nf_ * 2048;                       \
      bfr[nf_][0] = *(const bf16x8*)(smem + (CB) + r_);            \
      bfr[nf_][1] = *(const bf16x8*)(smem + (CB) + (r_ ^ 64));     \
    }                                                              \
  } while (0)

// 16 MFMA: acc rows 2Q,2Q+1 x 4 nf x 2 kk, A from set SET
#define MFMAQ(Q, SET) do {                                         \
    _Pragma("unroll")                                              \
    for (int nf_ = 0; nf_ < 4; ++nf_) {                            \
      _Pragma("unroll")                                            \
      for (int kk_ = 0; kk_ < 2; ++kk_) {                          \
        acc[2*(Q)][nf_] = __builtin_amdgcn_mfma_f32_16x16x32_bf16( \
            aA[SET][0][kk_], bfr[nf_][kk_], acc[2*(Q)][nf_], 0, 0, 0);   \
        acc[2*(Q)+1][nf_] = __builtin_amdgcn_mfma_f32_16x16x32_bf16(     \
            aA[SET][1][kk_], bfr[nf_][kk_], acc[2*(Q)+1][nf_], 0, 0, 0); \
      }                                                            \
    }                                                              \
  } while (0)

// stage one 128x64 half-tile: 2 x global_load_lds
__device__ __forceinline__ void stage_half_tile(const __bf16* gsrc, char* lds_dst) {
  gload_lds16(gsrc, lds_dst);
  gload_lds16(gsrc + 64 * 4096, lds_dst + 8192);
}

__global__ __launch_bounds__(512, 2) void gemm256_8ph(const __bf16* __restrict__ A,
                                                      const __bf16* __restrict__ B,
                                                      const float* __restrict__ bias,
                                                      float* __restrict__ C) {
  __shared__ __align__(16) char smem[131072];

  const int t    = threadIdx.x;          // 0..511
  const int wave = t >> 6;               // 0..7
  const int lane = t & 63;
  const int l16  = lane & 15;
  const int kg   = lane >> 4;            // 0..3
  const int wm   = wave >> 2;            // 0..1 (M half)
  const int wn   = wave & 3;             // 0..3 (N quarter)

  // XCD-aware bijective block swizzle (nwg = 512 = 8 x 64)
  const int orig = blockIdx.x;
  const int swz  = (orig & 7) * 64 + (orig >> 3);
  const int bn   = swz & 15;             // N/256 = 16 (fastest)
  const int bm   = swz >> 4;             // M/256 = 32

  // staging source (pre-swizzled): thread t covers row t>>3 (+s*64),
  // chunk c8 = (t&7) ^ ((t>>3)&7)
  const int c8 = (t & 7) ^ ((t >> 3) & 7);
  const __bf16* gA = A + ((size_t)(bm * 256 + (t >> 3))) * 4096 + c8 * 8;
  const __bf16* gB = B + ((size_t)(bn * 256 + (t >> 3))) * 4096 + c8 * 8;
  char* stw = smem + wave * 1024;        // + lane*16 implicit in gload_lds

  // ds_read byte offsets (swizzled): row = frag*16 + l16,
  // chunk bits [6:4] = kg ^ (l16&7); kk half via ^64 at use site
  const uint32_t ca = ((uint32_t)(kg ^ (l16 & 7))) << 4;
  const uint32_t a_rd = (uint32_t)(wm ? A1OFF : A0OFF) + (uint32_t)l16 * 128 + ca;
  const uint32_t b_rd = (uint32_t)(wn >= 2 ? B1OFF : B0OFF) +
                        (uint32_t)(wn & 1) * 8192 + (uint32_t)l16 * 128 + ca;

  f32x4 acc[8][4];
#pragma unroll
  for (int i = 0; i < 8; ++i)
#pragma unroll
    for (int j = 0; j < 4; ++j) acc[i][j] = (f32x4){0.f, 0.f, 0.f, 0.f};

  bf16x8 aA[2][2][2];   // [set][frag][kk] — all indices compile-time
  bf16x8 bfr[4][2];     // [nf][kk] — single set, WAR handled by issue order

  // ---- prologue: tile0 -> buf0 (8 loads), tile1 B + A0 -> buf1 (6 loads)
  stage_half_tile(gA,            stw + BUF0 + A0OFF);
  stage_half_tile(gA + AH1,      stw + BUF0 + A1OFF);
  stage_half_tile(gB,            stw + BUF0 + B0OFF);
  stage_half_tile(gB + AH1,      stw + BUF0 + B1OFF);
  stage_half_tile(gB + 64,       stw + BUF1 + B0OFF);
  stage_half_tile(gB + AH1 + 64, stw + BUF1 + B1OFF);
  stage_half_tile(gA + 64,       stw + BUF1 + A0OFF);
  WAIT_VM6();              // tile0's 8 loads landed; 6 stay in flight
  BARRIER();
  LDA2(0, BUF0, 0);        // peel: frags 0,1 for P0 (drained at P0 head)

  // ---- main loop: iter j computes tiles E=2j (buf0), O=2j+1 (buf1)
  for (int j = 0; j < NITER - 1; ++j) {
    const size_t kO  = (size_t)(2 * j + 1) * 64;
    const size_t kE2 = (size_t)(2 * j + 2) * 64;
    const size_t kO2 = (size_t)(2 * j + 3) * 64;
    // P0: MFMA acc0,1 (buf0, set0) | read B(buf0)+frags2,3->set1
    WAIT_LGKM0();
    LDB(BUF0);
    LDA2(1, BUF0, 2);
    LGKM4();
    PRIO1(); MFMAQ(0, 0); PRIO0();
    stage_half_tile(gA + AH1 + kO, stw + BUF1 + A1OFF);
    BARRIER();
    // P1
    WAIT_LGKM0();
    LDA2(0, BUF0, 4);
    PRIO1(); MFMAQ(1, 1); PRIO0();
    stage_half_tile(gB + kE2, stw + BUF0 + B0OFF);
    BARRIER();
    // P2
    WAIT_LGKM0();
    LDA2(1, BUF0, 6);
    PRIO1(); MFMAQ(2, 0); PRIO0();
    stage_half_tile(gB + AH1 + kE2, stw + BUF0 + B1OFF);
    WAIT_VM4();            // tile O (buf1) fully landed before P3/P4 reads
    BARRIER();
    // P3: last buf0 quadrant | read buf1 frags 0,1
    WAIT_LGKM0();
    LDA2(0, BUF1, 0);
    PRIO1(); MFMAQ(3, 1); PRIO0();
    stage_half_tile(gA + kE2, stw + BUF0 + A0OFF);
    BARRIER();
    // P4: first buf1 quadrant | read B(buf1)+frags2,3
    WAIT_LGKM0();
    LDB(BUF1);
    LDA2(1, BUF1, 2);
    LGKM4();
    PRIO1(); MFMAQ(0, 0); PRIO0();
    stage_half_tile(gA + AH1 + kE2, stw + BUF0 + A1OFF);
    BARRIER();
    // P5
    WAIT_LGKM0();
    LDA2(0, BUF1, 4);
    PRIO1(); MFMAQ(1, 1); PRIO0();
    stage_half_tile(gB + kO2, stw + BUF1 + B0OFF);
    BARRIER();
    // P6
    WAIT_LGKM0();
    LDA2(1, BUF1, 6);
    PRIO1(); MFMAQ(2, 0); PRIO0();
    stage_half_tile(gB + AH1 + kO2, stw + BUF1 + B1OFF);
    stage_half_tile(gA + kO2,       stw + BUF1 + A0OFF);
    WAIT_VM6();            // tile E+2 (buf0) fully landed before P7/next-P0
    BARRIER();
    // P7: last buf1 quadrant | read next tile's buf0 frags 0,1
    WAIT_LGKM0();
    LDA2(0, BUF0, 0);
    PRIO1(); MFMAQ(3, 1); PRIO0();
    BARRIER();
  }
  // ---- last iter (tiles 62 buf0, 63 buf1)
  {
    const size_t kO = (size_t)(2 * (NITER - 1) + 1) * 64;
    WAIT_LGKM0(); LDB(BUF0); LDA2(1, BUF0, 2); LGKM4();
    PRIO1(); MFMAQ(0, 0); PRIO0();
    stage_half_tile(gA + AH1 + kO, stw + BUF1 + A1OFF);
    BARRIER();
    WAIT_LGKM0(); LDA2(0, BUF0, 4);
    PRIO1(); MFMAQ(1, 1); PRIO0();
    BARRIER();
    WAIT_LGKM0(); LDA2(1, BUF0, 6);
    PRIO1(); MFMAQ(2, 0); PRIO0();
    WAIT_VM0();            // tile 63 fully landed
    BARRIER();
    WAIT_LGKM0(); LDA2(0, BUF1, 0);
    PRIO1(); MFMAQ(3, 1); PRIO0();
    BARRIER();
    WAIT_LGKM0(); LDB(BUF1); LDA2(1, BUF1, 2); LGKM4();
    PRIO1(); MFMAQ(0, 0); PRIO0();
    BARRIER();
    WAIT_LGKM0(); LDA2(0, BUF1, 4);
    PRIO1(); MFMAQ(1, 1); PRIO0();
    BARRIER();
    WAIT_LGKM0(); LDA2(1, BUF1, 6);
    PRIO1(); MFMAQ(2, 0); PRIO0();
    BARRIER();
    WAIT_LGKM0();
    PRIO1(); MFMAQ(3, 1); PRIO0();
  }

  // ---- epilogue: C/D layout col = lane&15 (n), row = kg*4 + reg (m)
#pragma unroll
  for (int mf = 0; mf < 8; ++mf) {
    const int m0 = bm * 256 + wm * 128 + mf * 16 + kg * 4;
#pragma unroll
    for (int nf = 0; nf < 4; ++nf) {
      const int n = bn * 256 + wn * 64 + nf * 16 + l16;
      const float bv = bias[n];
#pragma unroll
      for (int r = 0; r < 4; ++r)
        C[(size_t)(m0 + r) * N_DIM + n] = acc[mf][nf][r] + bv;
    }
  }
}

// ---------------- fallback: fused naive ----------------
__global__ __launch_bounds__(256) void naive_fused(const float* __restrict__ x,
                                                   const int* __restrict__ q,
                                                   const float* __restrict__ scales,
                                                   const float* __restrict__ bias,
                                                   float* __restrict__ out) {
  __shared__ float xs[K_DIM];
  const int m = blockIdx.y;
  const int n = blockIdx.x * 256 + threadIdx.x;
  for (int k = threadIdx.x; k < K_DIM; k += 256)
    xs[k] = x[(size_t)m * K_DIM + k];
  __syncthreads();

  const int4* q4 = reinterpret_cast<const int4*>(q) + (size_t)n * 512;
  float acc = 0.f, sc = 0.f;
  for (int c = 0; c < 512; ++c) {
    if ((c & 3) == 0) sc = scales[n * 128 + (c >> 2)];
    int4 v = q4[c];
    int b0 = v.x & 0xFF, b1 = v.y & 0xFF, b2 = v.z & 0xFF, b3 = v.w & 0xFF;
    int k = c * 8;
    acc += xs[k + 0] * fp4_to_f32((b0 >> 4) & 15) * sc;
    acc += xs[k + 1] * fp4_to_f32(b0 & 15) * sc;
    acc += xs[k + 2] * fp4_to_f32((b1 >> 4) & 15) * sc;
    acc += xs[k + 3] * fp4_to_f32(b1 & 15) * sc;
    acc += xs[k + 4] * fp4_to_f32((b2 >> 4) & 15) * sc;
    acc += xs[k + 5] * fp4_to_f32(b2 & 15) * sc;
    acc += xs[k + 6] * fp4_to_f32((b3 >> 4) & 15) * sc;
    acc += xs[k + 7] * fp4_to_f32(b3 & 15) * sc;
  }
  out[(size_t)m * N_DIM + n] = acc + bias[n];
}

// ---------------- launch ----------------
extern "C" void kernel_launch(void* const* d_in, const int* in_sizes, int n_in,
                              void* d_out, int out_size, void* d_ws, size_t ws_size,
                              hipStream_t stream) {
  const float* x    = (const float*)d_in[0];
  const int*   q    = (const int*)d_in[1];
  const float* sc   = (const float*)d_in[2];
  const float* bias = (const float*)d_in[3];
  float* out = (float*)d_out;

  const size_t xb_bytes = (size_t)M_DIM * K_DIM * 2;
  const size_t w_bytes  = (size_t)N_DIM * K_DIM * 2;

  if (ws_size >= xb_bytes + w_bytes) {
    uint32_t* xb = (uint32_t*)d_ws;
    uint32_t* W  = (uint32_t*)((char*)d_ws + xb_bytes);

    dequant_w<<<NBLK_W / 256, 256, 0, stream>>>(q, sc, W);
    cvt_x<<<(M_DIM * (size_t)K_DIM / 8) / 256, 256, 0, stream>>>(x, xb);

    gemm256_8ph<<<dim3(512), 512, 0, stream>>>((const __bf16*)xb, (const __bf16*)W, bias, out);
  } else {
    dim3 grid(N_DIM / 256, M_DIM);
    naive_fused<<<grid, 256, 0, stream>>>(x, q, sc, bias, out);
  }
}

// Round 6
// 278.263 us; speedup vs baseline: 1.3487x; 1.0133x over previous
//
#include <hip/hip_runtime.h>
#include <hip/hip_bf16.h>
#include <stdint.h>

// y[b,s,o] = sum_k x[b,s,k] * W[o,k] + bias[o]
// W from packed FP4 (E2M1 nibbles in int32 bytes) * per-32 fp32 scales.
// M = 8192, N = 4096, K = 4096.

#define M_DIM 8192
#define N_DIM 4096
#define K_DIM 4096
#define NBLK_W (N_DIM * K_DIM / 32)

typedef __bf16 bf16x8 __attribute__((ext_vector_type(8)));
typedef float  f32x4  __attribute__((ext_vector_type(4)));

// ---------------- helpers ----------------

__device__ __forceinline__ uint16_t f32_to_bf16_rn(float f) {
  uint32_t u = __float_as_uint(f);
  uint32_t r = (u + 0x7FFFu + ((u >> 16) & 1u)) >> 16;
  return (uint16_t)r;
}
__device__ __forceinline__ uint32_t pack_bf16x2(float e0, float e1) {
  return (uint32_t)f32_to_bf16_rn(e0) | ((uint32_t)f32_to_bf16_rn(e1) << 16);
}
__device__ __forceinline__ float fp4_to_f32(int nib) {
  uint32_t e = (uint32_t)(nib >> 1) & 3u;
  uint32_t m = (uint32_t)nib & 1u;
  uint32_t s = (uint32_t)(nib >> 3) & 1u;
  uint32_t bits = e ? (((126u + e) << 23) | (m << 22)) : (m ? 0x3F000000u : 0u);
  bits |= s << 31;
  return __uint_as_float(bits);
}
__device__ __forceinline__ void gload_lds16(const void* g, void* lds) {
  __builtin_amdgcn_global_load_lds(
      (const __attribute__((address_space(1))) unsigned int*)g,
      (__attribute__((address_space(3))) unsigned int*)lds,
      16, 0, 0);
}

// ---------------- kernel 1: dequant W -> bf16 [N][K] ----------------
__global__ __launch_bounds__(256) void dequant_w(const int* __restrict__ q,
                                                 const float* __restrict__ scales,
                                                 uint32_t* __restrict__ W) {
  int b = blockIdx.x * 256 + threadIdx.x;
  float sc = scales[b];
  const int4* q4 = reinterpret_cast<const int4*>(q) + (size_t)b * 4;
  int4* dst = reinterpret_cast<int4*>(W + (size_t)b * 16);
#pragma unroll
  for (int i = 0; i < 4; ++i) {
    int4 v = q4[i];
    int b0 = v.x & 0xFF, b1 = v.y & 0xFF, b2 = v.z & 0xFF, b3 = v.w & 0xFF;
    uint32_t p0 = pack_bf16x2(fp4_to_f32((b0 >> 4) & 15) * sc, fp4_to_f32(b0 & 15) * sc);
    uint32_t p1 = pack_bf16x2(fp4_to_f32((b1 >> 4) & 15) * sc, fp4_to_f32(b1 & 15) * sc);
    uint32_t p2 = pack_bf16x2(fp4_to_f32((b2 >> 4) & 15) * sc, fp4_to_f32(b2 & 15) * sc);
    uint32_t p3 = pack_bf16x2(fp4_to_f32((b3 >> 4) & 15) * sc, fp4_to_f32(b3 & 15) * sc);
    int4 o; o.x = (int)p0; o.y = (int)p1; o.z = (int)p2; o.w = (int)p3;
    dst[i] = o;
  }
}

// ---------------- kernel 2: cvt x fp32 -> bf16 ----------------
__global__ __launch_bounds__(256) void cvt_x(const float* __restrict__ x,
                                             uint32_t* __restrict__ xb) {
  size_t i = ((size_t)blockIdx.x * 256 + threadIdx.x) * 8;
  float4 a = *reinterpret_cast<const float4*>(x + i);
  float4 c = *reinterpret_cast<const float4*>(x + i + 4);
  int4 o;
  o.x = (int)pack_bf16x2(a.x, a.y);
  o.y = (int)pack_bf16x2(a.z, a.w);
  o.z = (int)pack_bf16x2(c.x, c.y);
  o.w = (int)pack_bf16x2(c.z, c.w);
  *reinterpret_cast<int4*>(xb + i / 2) = o;
}

// ---------------- kernel 3: 256x256 8-phase pipelined bf16 GEMM (B^T) ----
// 512 threads = 8 waves (2M x 4N). Per-wave 128x64 out, acc[8][4] f32x4.
// LDS 128 KiB: 2 bufs x {A0,A1,B0,B1 halves 128x64 bf16}.
// 3-bit row swizzle; pre-swizzled global source + swizzled ds_read addrs.
// Register pipelining (reads one phase early); ONE barrier/phase; counted
// vmcnt(4)@P2, vmcnt(6)@P6. B reads split: nf01 at tail of P7/P3 (after
// MFMA to avoid bfr WAR), nf23 at head of P0/P4 -> max burst 8 reads/wave.
// C written with nontemporal stores (write-once; keep L2/L3 for A/B).

#define BUF0 0
#define BUF1 65536
#define A0OFF 0
#define A1OFF 16384
#define B0OFF 32768
#define B1OFF 49152
#define AH1 (128 * 4096)       // +128 rows (elements)
#define NITER 32               // 64 K-tiles, 2 per iter

#define BARRIER()   asm volatile("s_barrier" ::: "memory")
#define WAIT_LGKM0() do { asm volatile("s_waitcnt lgkmcnt(0)" ::: "memory"); \
                          __builtin_amdgcn_sched_barrier(0); } while (0)
#define LGKM4()     do { asm volatile("s_waitcnt lgkmcnt(4)" ::: "memory"); \
                          __builtin_amdgcn_sched_barrier(0); } while (0)
#define WAIT_VM6()  asm volatile("s_waitcnt vmcnt(6)" ::: "memory")
#define WAIT_VM4()  asm volatile("s_waitcnt vmcnt(4)" ::: "memory")
#define WAIT_VM0()  asm volatile("s_waitcnt vmcnt(0)" ::: "memory")
#define PRIO1()     __builtin_amdgcn_s_setprio(1)
#define PRIO0()     __builtin_amdgcn_s_setprio(0)

// read A frags F, F+1 from buf CB into set SET (kk=1 chunk = addr ^ 64)
#define LDA2(SET, CB, F) do {                                      \
    const uint32_t r0_ = a_rd + (F) * 2048;                        \
    const uint32_t r1_ = a_rd + ((F) + 1) * 2048;                  \
    aA[SET][0][0] = *(const bf16x8*)(smem + (CB) + r0_);           \
    aA[SET][0][1] = *(const bf16x8*)(smem + (CB) + (r0_ ^ 64));    \
    aA[SET][1][0] = *(const bf16x8*)(smem + (CB) + r1_);           \
    aA[SET][1][1] = *(const bf16x8*)(smem + (CB) + (r1_ ^ 64));    \
  } while (0)

// read B frags NF, NF+1 (x2 kk) from buf CB
#define LDB2(CB, NF) do {                                          \
    _Pragma("unroll")                                              \
    for (int nf_ = (NF); nf_ < (NF) + 2; ++nf_) {                  \
      const uint32_t r_ = b_rd + nf_ * 2048;                       \
      bfr[nf_][0] = *(const bf16x8*)(smem + (CB) + r_);            \
      bfr[nf_][1] = *(const bf16x8*)(smem + (CB) + (r_ ^ 64));     \
    }                                                              \
  } while (0)

// 16 MFMA: acc rows 2Q,2Q+1 x 4 nf x 2 kk, A from set SET
#define MFMAQ(Q, SET) do {                                         \
    _Pragma("unroll")                                              \
    for (int nf_ = 0; nf_ < 4; ++nf_) {                            \
      _Pragma("unroll")                                            \
      for (int kk_ = 0; kk_ < 2; ++kk_) {                          \
        acc[2*(Q)][nf_] = __builtin_amdgcn_mfma_f32_16x16x32_bf16( \
            aA[SET][0][kk_], bfr[nf_][kk_], acc[2*(Q)][nf_], 0, 0, 0);   \
        acc[2*(Q)+1][nf_] = __builtin_amdgcn_mfma_f32_16x16x32_bf16(     \
            aA[SET][1][kk_], bfr[nf_][kk_], acc[2*(Q)+1][nf_], 0, 0, 0); \
      }                                                            \
    }                                                              \
  } while (0)

// stage one 128x64 half-tile: 2 x global_load_lds
__device__ __forceinline__ void stage_half_tile(const __bf16* gsrc, char* lds_dst) {
  gload_lds16(gsrc, lds_dst);
  gload_lds16(gsrc + 64 * 4096, lds_dst + 8192);
}

__global__ __launch_bounds__(512, 2) void gemm256_8ph(const __bf16* __restrict__ A,
                                                      const __bf16* __restrict__ B,
                                                      const float* __restrict__ bias,
                                                      float* __restrict__ C) {
  __shared__ __align__(16) char smem[131072];

  const int t    = threadIdx.x;          // 0..511
  const int wave = t >> 6;               // 0..7
  const int lane = t & 63;
  const int l16  = lane & 15;
  const int kg   = lane >> 4;            // 0..3
  const int wm   = wave >> 2;            // 0..1 (M half)
  const int wn   = wave & 3;             // 0..3 (N quarter)

  // XCD-aware bijective block swizzle (nwg = 512 = 8 x 64)
  const int orig = blockIdx.x;
  const int swz  = (orig & 7) * 64 + (orig >> 3);
  const int bn   = swz & 15;             // N/256 = 16 (fastest)
  const int bm   = swz >> 4;             // M/256 = 32

  // staging source (pre-swizzled): thread t covers row t>>3 (+s*64),
  // chunk c8 = (t&7) ^ ((t>>3)&7)
  const int c8 = (t & 7) ^ ((t >> 3) & 7);
  const __bf16* gA = A + ((size_t)(bm * 256 + (t >> 3))) * 4096 + c8 * 8;
  const __bf16* gB = B + ((size_t)(bn * 256 + (t >> 3))) * 4096 + c8 * 8;
  char* stw = smem + wave * 1024;        // + lane*16 implicit in gload_lds

  // ds_read byte offsets (swizzled): row = frag*16 + l16,
  // chunk bits [6:4] = kg ^ (l16&7); kk half via ^64 at use site
  const uint32_t ca = ((uint32_t)(kg ^ (l16 & 7))) << 4;
  const uint32_t a_rd = (uint32_t)(wm ? A1OFF : A0OFF) + (uint32_t)l16 * 128 + ca;
  const uint32_t b_rd = (uint32_t)(wn >= 2 ? B1OFF : B0OFF) +
                        (uint32_t)(wn & 1) * 8192 + (uint32_t)l16 * 128 + ca;

  f32x4 acc[8][4];
#pragma unroll
  for (int i = 0; i < 8; ++i)
#pragma unroll
    for (int j = 0; j < 4; ++j) acc[i][j] = (f32x4){0.f, 0.f, 0.f, 0.f};

  bf16x8 aA[2][2][2];   // [set][frag][kk]
  bf16x8 bfr[4][2];     // [nf][kk]

  // ---- prologue: tile0 -> buf0 (8 loads), tile1 B + A0 -> buf1 (6 loads)
  stage_half_tile(gA,            stw + BUF0 + A0OFF);
  stage_half_tile(gA + AH1,      stw + BUF0 + A1OFF);
  stage_half_tile(gB,            stw + BUF0 + B0OFF);
  stage_half_tile(gB + AH1,      stw + BUF0 + B1OFF);
  stage_half_tile(gB + 64,       stw + BUF1 + B0OFF);
  stage_half_tile(gB + AH1 + 64, stw + BUF1 + B1OFF);
  stage_half_tile(gA + 64,       stw + BUF1 + A0OFF);
  WAIT_VM6();              // tile0's 8 loads landed; 6 stay in flight
  BARRIER();
  LDA2(0, BUF0, 0);        // peel: A frags 0,1 + B nf 0,1 for P0
  LDB2(BUF0, 0);

  // ---- main loop: iter j computes tiles E=2j (buf0), O=2j+1 (buf1)
  for (int j = 0; j < NITER - 1; ++j) {
    const size_t kO  = (size_t)(2 * j + 1) * 64;
    const size_t kE2 = (size_t)(2 * j + 2) * 64;
    const size_t kO2 = (size_t)(2 * j + 3) * 64;
    // P0
    WAIT_LGKM0();
    LDB2(BUF0, 2);
    LDA2(1, BUF0, 2);
    LGKM4();
    PRIO1(); MFMAQ(0, 0); PRIO0();
    stage_half_tile(gA + AH1 + kO, stw + BUF1 + A1OFF);
    BARRIER();
    // P1
    WAIT_LGKM0();
    LDA2(0, BUF0, 4);
    PRIO1(); MFMAQ(1, 1); PRIO0();
    stage_half_tile(gB + kE2, stw + BUF0 + B0OFF);
    BARRIER();
    // P2
    WAIT_LGKM0();
    LDA2(1, BUF0, 6);
    PRIO1(); MFMAQ(2, 0); PRIO0();
    stage_half_tile(gB + AH1 + kE2, stw + BUF0 + B1OFF);
    WAIT_VM4();            // tile O (buf1) fully landed before P3/P4 reads
    BARRIER();
    // P3: last buf0 quadrant | read buf1 A frags 0,1; B nf01 after MFMA
    WAIT_LGKM0();
    LDA2(0, BUF1, 0);
    PRIO1(); MFMAQ(3, 1); PRIO0();
    LDB2(BUF1, 0);
    stage_half_tile(gA + kE2, stw + BUF0 + A0OFF);
    BARRIER();
    // P4
    WAIT_LGKM0();
    LDB2(BUF1, 2);
    LDA2(1, BUF1, 2);
    LGKM4();
    PRIO1(); MFMAQ(0, 0); PRIO0();
    stage_half_tile(gA + AH1 + kE2, stw + BUF0 + A1OFF);
    BARRIER();
    // P5
    WAIT_LGKM0();
    LDA2(0, BUF1, 4);
    PRIO1(); MFMAQ(1, 1); PRIO0();
    stage_half_tile(gB + kO2, stw + BUF1 + B0OFF);
    BARRIER();
    // P6
    WAIT_LGKM0();
    LDA2(1, BUF1, 6);
    PRIO1(); MFMAQ(2, 0); PRIO0();
    stage_half_tile(gB + AH1 + kO2, stw + BUF1 + B1OFF);
    stage_half_tile(gA + kO2,       stw + BUF1 + A0OFF);
    WAIT_VM6();            // tile E+2 (buf0) fully landed
    BARRIER();
    // P7: last buf1 quadrant | read next buf0 A frags 0,1; B nf01 after MFMA
    WAIT_LGKM0();
    LDA2(0, BUF0, 0);
    PRIO1(); MFMAQ(3, 1); PRIO0();
    LDB2(BUF0, 0);
    BARRIER();
  }
  // ---- last iter (tiles 62 buf0, 63 buf1)
  {
    const size_t kO = (size_t)(2 * (NITER - 1) + 1) * 64;
    WAIT_LGKM0(); LDB2(BUF0, 2); LDA2(1, BUF0, 2); LGKM4();
    PRIO1(); MFMAQ(0, 0); PRIO0();
    stage_half_tile(gA + AH1 + kO, stw + BUF1 + A1OFF);
    BARRIER();
    WAIT_LGKM0(); LDA2(0, BUF0, 4);
    PRIO1(); MFMAQ(1, 1); PRIO0();
    BARRIER();
    WAIT_LGKM0(); LDA2(1, BUF0, 6);
    PRIO1(); MFMAQ(2, 0); PRIO0();
    WAIT_VM0();            // tile 63 fully landed
    BARRIER();
    WAIT_LGKM0(); LDA2(0, BUF1, 0);
    PRIO1(); MFMAQ(3, 1); PRIO0();
    LDB2(BUF1, 0);
    BARRIER();
    WAIT_LGKM0(); LDB2(BUF1, 2); LDA2(1, BUF1, 2); LGKM4();
    PRIO1(); MFMAQ(0, 0); PRIO0();
    BARRIER();
    WAIT_LGKM0(); LDA2(0, BUF1, 4);
    PRIO1(); MFMAQ(1, 1); PRIO0();
    BARRIER();
    WAIT_LGKM0(); LDA2(1, BUF1, 6);
    PRIO1(); MFMAQ(2, 0); PRIO0();
    BARRIER();
    WAIT_LGKM0();
    PRIO1(); MFMAQ(3, 1); PRIO0();
  }

  // ---- epilogue: C/D layout col = lane&15 (n), row = kg*4 + reg (m)
  // nontemporal stores: C is write-once, keep it out of L2/L3
#pragma unroll
  for (int mf = 0; mf < 8; ++mf) {
    const int m0 = bm * 256 + wm * 128 + mf * 16 + kg * 4;
#pragma unroll
    for (int nf = 0; nf < 4; ++nf) {
      const int n = bn * 256 + wn * 64 + nf * 16 + l16;
      const float bv = bias[n];
#pragma unroll
      for (int r = 0; r < 4; ++r)
        __builtin_nontemporal_store(acc[mf][nf][r] + bv,
                                    &C[(size_t)(m0 + r) * N_DIM + n]);
    }
  }
}

// ---------------- fallback: fused naive ----------------
__global__ __launch_bounds__(256) void naive_fused(const float* __restrict__ x,
                                                   const int* __restrict__ q,
                                                   const float* __restrict__ scales,
                                                   const float* __restrict__ bias,
                                                   float* __restrict__ out) {
  __shared__ float xs[K_DIM];
  const int m = blockIdx.y;
  const int n = blockIdx.x * 256 + threadIdx.x;
  for (int k = threadIdx.x; k < K_DIM; k += 256)
    xs[k] = x[(size_t)m * K_DIM + k];
  __syncthreads();

  const int4* q4 = reinterpret_cast<const int4*>(q) + (size_t)n * 512;
  float acc = 0.f, sc = 0.f;
  for (int c = 0; c < 512; ++c) {
    if ((c & 3) == 0) sc = scales[n * 128 + (c >> 2)];
    int4 v = q4[c];
    int b0 = v.x & 0xFF, b1 = v.y & 0xFF, b2 = v.z & 0xFF, b3 = v.w & 0xFF;
    int k = c * 8;
    acc += xs[k + 0] * fp4_to_f32((b0 >> 4) & 15) * sc;
    acc += xs[k + 1] * fp4_to_f32(b0 & 15) * sc;
    acc += xs[k + 2] * fp4_to_f32((b1 >> 4) & 15) * sc;
    acc += xs[k + 3] * fp4_to_f32(b1 & 15) * sc;
    acc += xs[k + 4] * fp4_to_f32((b2 >> 4) & 15) * sc;
    acc += xs[k + 5] * fp4_to_f32(b2 & 15) * sc;
    acc += xs[k + 6] * fp4_to_f32((b3 >> 4) & 15) * sc;
    acc += xs[k + 7] * fp4_to_f32(b3 & 15) * sc;
  }
  out[(size_t)m * N_DIM + n] = acc + bias[n];
}

// ---------------- launch ----------------
extern "C" void kernel_launch(void* const* d_in, const int* in_sizes, int n_in,
                              void* d_out, int out_size, void* d_ws, size_t ws_size,
                              hipStream_t stream) {
  const float* x    = (const float*)d_in[0];
  const int*   q    = (const int*)d_in[1];
  const float* sc   = (const float*)d_in[2];
  const float* bias = (const float*)d_in[3];
  float* out = (float*)d_out;

  const size_t xb_bytes = (size_t)M_DIM * K_DIM * 2;
  const size_t w_bytes  = (size_t)N_DIM * K_DIM * 2;

  if (ws_size >= xb_bytes + w_bytes) {
    uint32_t* xb = (uint32_t*)d_ws;
    uint32_t* W  = (uint32_t*)((char*)d_ws + xb_bytes);

    dequant_w<<<NBLK_W / 256, 256, 0, stream>>>(q, sc, W);
    cvt_x<<<(M_DIM * (size_t)K_DIM / 8) / 256, 256, 0, stream>>>(x, xb);

    gemm256_8ph<<<dim3(512), 512, 0, stream>>>((const __bf16*)xb, (const __bf16*)W, bias, out);
  } else {
    dim3 grid(N_DIM / 256, M_DIM);
    naive_fused<<<grid, 256, 0, stream>>>(x, q, sc, bias, out);
  }
}